// Round 5
// baseline (400.033 us; speedup 1.0000x reference)
//
#include <hip/hip_runtime.h>
#include <stdint.h>

#define S_LEN 2048
#define HDIM  2048
#define N_HEADS 16
#define HEAD_D 128
#define N_KV 4

typedef unsigned short u16;
typedef __attribute__((ext_vector_type(8))) short bf16x8;
typedef __attribute__((ext_vector_type(4))) short bf16x4;
typedef __attribute__((ext_vector_type(4))) float f32x4;

// K=16 bf16 MFMA (v_mfma_f32_16x16x16_bf16, 2 A-regs = bf16x4 operands).
#define MFMA_PV(a, b, c) __builtin_amdgcn_mfma_f32_16x16x16bf16_1k(a, b, c, 0, 0, 0)

__device__ __forceinline__ u16 f2bf(float f) {
  unsigned u = __float_as_uint(f);
  u += 0x7FFFu + ((u >> 16) & 1u);
  return (u16)(u >> 16);
}

__device__ __forceinline__ float bf2f(u16 v) {
  return __uint_as_float(((unsigned)v) << 16);
}

__device__ __forceinline__ void gll16(void* lds, const void* gp) {
  __builtin_amdgcn_global_load_lds(
      (const __attribute__((address_space(1))) void*)gp,
      (__attribute__((address_space(3))) void*)lds, 16, 0, 0);
}

// ---------------- fp32 -> bf16 convert (vectorized) ----------------
__global__ __launch_bounds__(256) void k_convert(const float* __restrict__ src,
                                                 u16* __restrict__ dst, int n4) {
  int i = blockIdx.x * 256 + threadIdx.x;
  if (i < n4) {
    float4 v = ((const float4*)src)[i];
    ushort4 o;
    o.x = f2bf(v.x); o.y = f2bf(v.y); o.z = f2bf(v.z); o.w = f2bf(v.w);
    ((ushort4*)dst)[i] = o;
  }
}

// ---------------- W [K][N] fp32 -> Wt [N][K] bf16 ----------------
// perm!=0: remap output row within each 128-col head block by
// pi(d) = (d&15) | ((d&48)<<1) | ((d&64)>>2). This puts rope partners
// (d, d+64) at cols (c, c+16) so the fused GEMM epilogue holds both in
// adjacent acc fragments (j=2jp, 2jp+1). Inverse (epilogue side):
// d = (c&15) + ((c>>5)<<4) + ((c&16)<<2).
__global__ __launch_bounds__(256) void k_transpose_w(const float* __restrict__ W,
                                                     u16* __restrict__ Wt,
                                                     int K, int N, int perm) {
  __shared__ float tile[64][65];
  int k0 = blockIdx.x * 64, n0 = blockIdx.y * 64;
  int tr = threadIdx.x >> 6, tc = threadIdx.x & 63;
#pragma unroll
  for (int i = 0; i < 16; ++i) {
    int r = tr + i * 4;
    tile[r][tc] = W[(size_t)(k0 + r) * N + n0 + tc];
  }
  __syncthreads();
#pragma unroll
  for (int i = 0; i < 16; ++i) {
    int r = tr + i * 4;  // n offset
    int nn = n0 + r;
    if (perm)
      nn = (nn & ~127) | ((nn & 15) | ((nn & 48) << 1) | ((nn & 64) >> 2));
    Wt[(size_t)nn * K + k0 + tc] = f2bf(tile[tc][r]);
  }
}

// ---------------- 128x128 bf16 MFMA GEMM mainloop (A[M][K], Bt[N][K]) ----------------
__device__ __forceinline__ void gemm_main_128(
    const u16* __restrict__ A, const u16* __restrict__ Bt,
    int m0, int n0, int K, f32x4 (&acc)[4][4]) {
  __shared__ __align__(16) u16 sA[128 * 32];
  __shared__ __align__(16) u16 sB[128 * 32];
  const int tid = threadIdx.x;
  const int lane = tid & 63;
  const int wave = tid >> 6;
  const int quad = lane >> 4;
  const int l15 = lane & 15;
  const int wm = (wave >> 1) << 6;
  const int wn = (wave & 1) << 6;

#pragma unroll
  for (int i = 0; i < 4; ++i)
#pragma unroll
    for (int j = 0; j < 4; ++j)
      acc[i][j] = (f32x4){0.f, 0.f, 0.f, 0.f};

  for (int kk = 0; kk < K; kk += 32) {
    __syncthreads();
#pragma unroll
    for (int it = 0; it < 2; ++it) {
      int c = tid + (it << 8);     // 512 chunks of 16B per tile
      int row = c >> 2;
      int ko = (c & 3) << 3;
      gll16((char*)sA + c * 16, A + (size_t)(m0 + row) * K + kk + ko);
      gll16((char*)sB + c * 16, Bt + (size_t)(n0 + row) * K + kk + ko);
    }
    __syncthreads();
    bf16x8 af[4], bfr[4];
#pragma unroll
    for (int i = 0; i < 4; ++i)
      af[i] = *(const bf16x8*)&sA[(wm + (i << 4) + l15) * 32 + quad * 8];
#pragma unroll
    for (int j = 0; j < 4; ++j)
      bfr[j] = *(const bf16x8*)&sB[(wn + (j << 4) + l15) * 32 + quad * 8];
#pragma unroll
    for (int i = 0; i < 4; ++i)
#pragma unroll
      for (int j = 0; j < 4; ++j)
        acc[i][j] = __builtin_amdgcn_mfma_f32_16x16x32_bf16(af[i], bfr[j], acc[i][j], 0, 0, 0);
  }
}

// mainloop + standard fp32 epilogue (used by k_gemm_o)
__device__ __forceinline__ void gemm_tile_128(
    const u16* __restrict__ A, const u16* __restrict__ Bt,
    const float* __restrict__ bias, float* __restrict__ C,
    int m0, int n0, int K, int ldc) {
  const int tid = threadIdx.x;
  const int lane = tid & 63;
  const int wave = tid >> 6;
  const int quad = lane >> 4;
  const int l15 = lane & 15;
  const int wm = (wave >> 1) << 6;
  const int wn = (wave & 1) << 6;

  f32x4 acc[4][4];
  gemm_main_128(A, Bt, m0, n0, K, acc);

#pragma unroll
  for (int i = 0; i < 4; ++i) {
    int row = m0 + wm + (i << 4) + quad * 4;
#pragma unroll
    for (int j = 0; j < 4; ++j) {
      int col = n0 + wn + (j << 4) + l15;
      float bv = bias[col];
      float* cp = C + (size_t)row * ldc + col;
#pragma unroll
      for (int r = 0; r < 4; ++r)
        cp[(size_t)r * ldc] = acc[i][j][r] + bv;
    }
  }
}

// ---------------- QKV GEMM with fused RoPE epilogue for Q/K ----------------
// Wqt/Wkt rows are pi-permuted (see k_transpose_w), so thread fragment pair
// (j=2jp, j=2jp+1) holds rope partners (d1, d1+64) with
// d1 = ((wn>>5)+jp)*16 + l15 in [0,64). RoPE is applied in-register and the
// result written directly as Qbf bf16 [b,h,s,d] / Kbf bf16 [b,kvh,s,d] +
// past_key fp32. Eliminates k_rope and the Qf/Kf fp32 round-trips (~84 MB).
// Numerically identical to the old path: same fp32 acc+bias, same rope math.
__global__ __launch_bounds__(256) void k_gemm_qkv_fused(
    const u16* __restrict__ X, const u16* __restrict__ Wqt,
    const u16* __restrict__ Wkt, const u16* __restrict__ Wvt,
    const float* __restrict__ bq, const float* __restrict__ bk,
    const float* __restrict__ bv, u16* __restrict__ Qbf,
    u16* __restrict__ Kbf, float* __restrict__ outK,
    float* __restrict__ Vf) {
  const int m0 = blockIdx.x << 7;
  const int by = blockIdx.y;
  const int tid = threadIdx.x;
  const int lane = tid & 63;
  const int wave = tid >> 6;
  const int quad = lane >> 4;
  const int l15 = lane & 15;
  const int wm = (wave >> 1) << 6;
  const int wn = (wave & 1) << 6;

  const u16* Bt; int n0;
  if (by < 16)      { Bt = Wqt; n0 = by << 7; }
  else if (by < 20) { Bt = Wkt; n0 = (by - 16) << 7; }
  else              { Bt = Wvt; n0 = (by - 20) << 7; }

  f32x4 acc[4][4];
  gemm_main_128(X, Bt, m0, n0, 2048, acc);

  const float c1 = -13.287712379549449f / 64.f; // -log2(10000)/64

  if (by < 16) {
    // Q: rope + fold 1/sqrt(128)*log2(e), write bf16 [b,h,s,d]
    const float qscale = 0.08838834764831845f * 1.4426950408889634f;
    const int h = by;
#pragma unroll
    for (int jp = 0; jp < 2; ++jp) {
      const int d1 = (((wn >> 5) + jp) << 4) + l15;   // 0..63
      const float b1 = bq[h * 128 + d1];
      const float b2 = bq[h * 128 + d1 + 64];
      const float fr = exp2f((float)d1 * c1);
#pragma unroll
      for (int i = 0; i < 4; ++i) {
        const int rowb = m0 + wm + (i << 4) + quad * 4;
#pragma unroll
        for (int r = 0; r < 4; ++r) {
          const int tok = rowb + r;
          const int b = tok >> 11, s = tok & 2047;
          float sn, cs;
          sincosf((float)s * fr, &sn, &cs);
          float x1 = acc[i][2 * jp][r] + b1;
          float x2 = acc[i][2 * jp + 1][r] + b2;
          u16* dst = Qbf + ((size_t)(b * N_HEADS + h) * S_LEN + s) * HEAD_D + d1;
          dst[0]  = f2bf((x1 * cs - x2 * sn) * qscale);
          dst[64] = f2bf((x1 * sn + x2 * cs) * qscale);
        }
      }
    }
  } else if (by < 20) {
    // K: rope, write bf16 [b,kvh,s,d] + past_key fp32
    const int kvh = by - 16;
#pragma unroll
    for (int jp = 0; jp < 2; ++jp) {
      const int d1 = (((wn >> 5) + jp) << 4) + l15;
      const float b1 = bk[kvh * 128 + d1];
      const float b2 = bk[kvh * 128 + d1 + 64];
      const float fr = exp2f((float)d1 * c1);
#pragma unroll
      for (int i = 0; i < 4; ++i) {
        const int rowb = m0 + wm + (i << 4) + quad * 4;
#pragma unroll
        for (int r = 0; r < 4; ++r) {
          const int tok = rowb + r;
          const int b = tok >> 11, s = tok & 2047;
          float sn, cs;
          sincosf((float)s * fr, &sn, &cs);
          float x1 = acc[i][2 * jp][r] + b1;
          float x2 = acc[i][2 * jp + 1][r] + b2;
          float o1 = x1 * cs - x2 * sn;
          float o2 = x1 * sn + x2 * cs;
          size_t idx = ((size_t)(b * N_KV + kvh) * S_LEN + s) * HEAD_D + d1;
          Kbf[idx]      = f2bf(o1);
          Kbf[idx + 64] = f2bf(o2);
          outK[idx]      = o1;
          outK[idx + 64] = o2;
        }
      }
    }
  } else {
    // V: standard fp32 epilogue -> Vf [b*s][512]
#pragma unroll
    for (int i = 0; i < 4; ++i) {
      int row = m0 + wm + (i << 4) + quad * 4;
#pragma unroll
      for (int j = 0; j < 4; ++j) {
        int col = n0 + wn + (j << 4) + l15;
        float bvv = bv[col];
        float* cp = Vf + (size_t)row * 512 + col;
#pragma unroll
        for (int r = 0; r < 4; ++r)
          cp[(size_t)r * 512] = acc[i][j][r] + bvv;
      }
    }
  }
}

__global__ __launch_bounds__(256) void k_gemm_o(
    const u16* __restrict__ A, const u16* __restrict__ Wot,
    const float* __restrict__ bo, float* __restrict__ C) {
  gemm_tile_128(A, Wot, bo, C, blockIdx.x << 7, blockIdx.y << 7, 2048, 2048);
}

// ---------------- V: Vf fp32 [b,s,kvh*d] -> Vt bf16 [b,kvh,d,s] + past_value fp32 ----------------
__global__ __launch_bounds__(256) void k_vtrans(const float* __restrict__ Vf,
                                                u16* __restrict__ Vt,
                                                float* __restrict__ outV) {
  __shared__ float tile[64][65];
  int s0 = blockIdx.x * 64, d0 = blockIdx.y * 64;
  int z = blockIdx.z;                 // b*N_KV + kvh
  int b = z >> 2, kvh = z & 3;
  int tr = threadIdx.x >> 6, tc = threadIdx.x & 63;
#pragma unroll
  for (int i = 0; i < 16; ++i) {
    int r = tr + i * 4;   // s offset
    float v = Vf[(size_t)(b * S_LEN + s0 + r) * 512 + kvh * 128 + d0 + tc];
    tile[r][tc] = v;
    outV[((size_t)z * S_LEN + s0 + r) * HEAD_D + d0 + tc] = v;
  }
  __syncthreads();
#pragma unroll
  for (int i = 0; i < 16; ++i) {
    int r = tr + i * 4;   // d offset
    Vt[((size_t)z * HEAD_D + d0 + r) * S_LEN + s0 + tc] = f2bf(tile[tc][r]);
  }
}

// ---------------- flash attention, S^T formulation, split-KV ----------------
// Reverted verbatim to the round-0 form (84.5 us measured): single-buffered
// staging, no setprio, heavy-first by decode. r1-r4 established: (256,3)
// spills 211 MB (175 us); plain (256) floats to 172 VGPR / 2 waves-SIMD
// (123 us); constant-sum decode is -4% (LPT heavy-first wins); dbuf+counted
// vmcnt is -7% (2-blocks/CU already hides staging). (256,2) is the sweet spot.
__global__ __launch_bounds__(256, 2) void k_attn(
    const u16* __restrict__ Qbf, const u16* __restrict__ Kbf,
    const u16* __restrict__ Vt, u16* __restrict__ attn,
    u16* __restrict__ pO, float* __restrict__ pML) {
  __shared__ __align__(16) u16 smem[17920];   // 35840 B
  u16* sK = smem;            // 64 x 136  (8704)
  u16* sV = smem + 8704;     // 128 x 72  (9216)

  const int tid = threadIdx.x;
  const int lane = tid & 63;
  const int wave = tid >> 6;
  const int quad = lane >> 4;
  const int l15 = lane & 15;

  const int by = blockIdx.y;
  int qt, t0, t1, slot;
  bool finalw;
  if (by < 8) {               // heavy chunk0: 16 tiles, below-diagonal only
    qt = 8 + by; t0 = 0; t1 = 16; finalw = false;
    slot = ((blockIdx.x << 3) + (qt - 8)) << 1;
  } else {
    qt = 23 - by;
    if (qt >= 8) {            // heavy chunk1: diagonal part
      t0 = 16; t1 = 2 * qt + 2; finalw = false;
      slot = (((blockIdx.x << 3) + (qt - 8)) << 1) + 1;
    } else {                  // light q-tile: whole row, direct final write
      t0 = 0; t1 = 2 * qt + 2; finalw = true; slot = 0;
    }
  }

  const int bh = blockIdx.x;
  const int b = bh >> 4;
  const int h = bh & 15;
  const int kvh = h >> 2;
  const int q0 = qt << 7;
  const int qw = q0 + wave * 32;      // this wave's first q row

  const u16* Qb = Qbf + ((size_t)(b * N_HEADS + h) * S_LEN + qw) * HEAD_D;
  const u16* Kb = Kbf + (size_t)(b * N_KV + kvh) * S_LEN * HEAD_D;
  const u16* Vb = Vt + (size_t)(b * N_KV + kvh) * HEAD_D * S_LEN;

  // Q fragments (B-operand: lane holds Q[q=l15][d=quad*8+j]) for 2 row-groups
  bf16x8 aq[2][4];
#pragma unroll
  for (int i = 0; i < 2; ++i)
#pragma unroll
    for (int kc = 0; kc < 4; ++kc)
      aq[i][kc] = *(const bf16x8*)(Qb + (size_t)(i * 16 + l15) * HEAD_D + kc * 32 + quad * 8);

  float mst[2] = {-1e30f, -1e30f}, lst[2] = {0.f, 0.f};
  f32x4 oacc[2][8];
#pragma unroll
  for (int i = 0; i < 2; ++i)
#pragma unroll
    for (int n = 0; n < 8; ++n) oacc[i][n] = (f32x4){0.f, 0.f, 0.f, 0.f};

  for (int t = t0; t < t1; ++t) {
    const int kt0 = t << 6;
    __syncthreads();
    // stage K (64x17 chunks = 1088) + V (128x9 = 1152)
#pragma unroll
    for (int it = 0; it < 9; ++it) {
      int c = tid + (it << 8);
      if (c < 1088) {
        int row = c / 17;
        int k16 = c - row * 17;
        gll16((char*)sK + c * 16, Kb + (size_t)(kt0 + row) * HEAD_D + k16 * 8);
      } else if (c < 2240) {
        int vv = c - 1088;
        int d = vv / 9;
        int s16 = vv - d * 9;
        gll16((char*)sV + vv * 16, Vb + (size_t)d * S_LEN + kt0 + s16 * 8);
      }
    }
    __syncthreads();

    if (kt0 > qw + 31) continue;      // fully-masked for this wave (uniform branch)

    // S^T = K * Q^T : lane holds S[q=l15][s=quad*4+r] per 16x16 j-tile
    f32x4 st[2][4];
#pragma unroll
    for (int i = 0; i < 2; ++i)
#pragma unroll
      for (int j = 0; j < 4; ++j) st[i][j] = (f32x4){0.f, 0.f, 0.f, 0.f};
#pragma unroll
    for (int kc = 0; kc < 4; ++kc) {
#pragma unroll
      for (int j = 0; j < 4; ++j) {
        bf16x8 kf = *(const bf16x8*)&sK[(j * 16 + l15) * 136 + kc * 32 + quad * 8];
#pragma unroll
        for (int i = 0; i < 2; ++i)
          st[i][j] = __builtin_amdgcn_mfma_f32_16x16x32_bf16(kf, aq[i][kc], st[i][j], 0, 0, 0);
      }
    }

    if (kt0 + 63 > qw) {              // diagonal region: causal mask
#pragma unroll
      for (int i = 0; i < 2; ++i) {
        int q = qw + i * 16 + l15;
#pragma unroll
        for (int j = 0; j < 4; ++j) {
          int s = kt0 + j * 16 + quad * 4;
#pragma unroll
          for (int r = 0; r < 4; ++r)
            if (s + r > q) st[i][j][r] = -1e9f;
        }
      }
    }

    // online softmax; row stats live per-lane (q=l15), replicated across quads
    bf16x4 pf[2][4];
    float al[2];
#pragma unroll
    for (int i = 0; i < 2; ++i) {
      float m = -1e30f;
#pragma unroll
      for (int j = 0; j < 4; ++j)
#pragma unroll
        for (int r = 0; r < 4; ++r) m = fmaxf(m, st[i][j][r]);
      m = fmaxf(m, __shfl_xor(m, 16, 64));
      m = fmaxf(m, __shfl_xor(m, 32, 64));
      float mn = fmaxf(mst[i], m);
      al[i] = exp2f(mst[i] - mn);
      mst[i] = mn;
      float rs = 0.f;
#pragma unroll
      for (int j = 0; j < 4; ++j) {
        float p0 = exp2f(st[i][j][0] - mn);
        float p1 = exp2f(st[i][j][1] - mn);
        float p2 = exp2f(st[i][j][2] - mn);
        float p3 = exp2f(st[i][j][3] - mn);
        rs += (p0 + p1) + (p2 + p3);
        // pack 4 fp32 -> 4 bf16 via v_perm (half-up rounding)
        union { unsigned u[2]; bf16x4 v; } pk;
        pk.u[0] = __builtin_amdgcn_perm(__float_as_uint(p1) + 0x8000u,
                                        __float_as_uint(p0) + 0x8000u, 0x07060302u);
        pk.u[1] = __builtin_amdgcn_perm(__float_as_uint(p3) + 0x8000u,
                                        __float_as_uint(p2) + 0x8000u, 0x07060302u);
        pf[i][j] = pk.v;
      }
      rs += __shfl_xor(rs, 16, 64);
      rs += __shfl_xor(rs, 32, 64);
      lst[i] = lst[i] * al[i] + rs;
      // rescale O: rows of oacc are q=quad*4+r, fetch al for that row
#pragma unroll
      for (int r = 0; r < 4; ++r) {
        float a = __shfl(al[i], quad * 4 + r, 16);
#pragma unroll
        for (int n = 0; n < 8; ++n) oacc[i][n][r] *= a;
      }
    }

    // O += P*V via K=16 MFMA; P is already in A-layout in registers
#pragma unroll
    for (int j = 0; j < 4; ++j) {
#pragma unroll
      for (int n = 0; n < 8; ++n) {
        bf16x4 vf = *(const bf16x4*)&sV[(n * 16 + l15) * 72 + j * 16 + quad * 4];
#pragma unroll
        for (int i = 0; i < 2; ++i)
          oacc[i][n] = MFMA_PV(pf[i][j], vf, oacc[i][n]);
      }
    }
  }

  if (finalw) {
    // normalize + write [b, s, h, d] bf16 for the O-projection
#pragma unroll
    for (int i = 0; i < 2; ++i)
#pragma unroll
      for (int r = 0; r < 4; ++r) {
        float inv = 1.0f / __shfl(lst[i], quad * 4 + r, 16);
        int row = qw + i * 16 + quad * 4 + r;
        u16* op = attn + ((size_t)b * S_LEN + row) * HDIM + h * HEAD_D;
#pragma unroll
        for (int n = 0; n < 8; ++n)
          op[n * 16 + l15] = f2bf(oacc[i][n][r] * inv);
      }
  } else {
    // unnormalized partial O (bf16) + per-row m,l
    u16* po = pO + (size_t)slot * 16384;
#pragma unroll
    for (int i = 0; i < 2; ++i)
#pragma unroll
      for (int r = 0; r < 4; ++r) {
        int row = wave * 32 + i * 16 + quad * 4 + r;
#pragma unroll
        for (int n = 0; n < 8; ++n)
          po[row * 128 + n * 16 + l15] = f2bf(oacc[i][n][r]);
      }
    if (quad == 0) {
      float* ml = pML + slot * 256;
#pragma unroll
      for (int i = 0; i < 2; ++i) {
        int row = wave * 32 + i * 16 + l15;
        ml[row] = mst[i];
        ml[128 + row] = lst[i];
      }
    }
  }
}

// ---------------- combine the two partials of each heavy q-tile ----------------
__global__ __launch_bounds__(256) void k_attn_combine(
    const u16* __restrict__ pO, const float* __restrict__ pML,
    u16* __restrict__ attn) {
  const int bh = blockIdx.x;          // b*16 + h
  const int qt = 8 + blockIdx.y;
  const int b = bh >> 4;
  const int h = bh & 15;
  const int s0 = ((bh << 3) + blockIdx.y) << 1;   // slot pair base
  const int row = threadIdx.x >> 1;               // 0..127
  const int half = threadIdx.x & 1;               // 0..1 (64 cols each)

  const float* ml0 = pML + s0 * 256;
  const float* ml1 = pML + (s0 + 1) * 256;
  float m0 = ml0[row], l0 = ml0[128 + row];
  float m1 = ml1[row], l1 = ml1[128 + row];
  float m = fmaxf(m0, m1);
  float w0 = exp2f(m0 - m), w1 = exp2f(m1 - m);
  float inv = 1.0f / (l0 * w0 + l1 * w1);
  w0 *= inv; w1 *= inv;

  const u16* o0 = pO + (size_t)s0 * 16384 + row * 128 + half * 64;
  const u16* o1 = o0 + 16384;
  u16* op = attn + ((size_t)(b * S_LEN + (qt << 7) + row)) * HDIM + h * HEAD_D + half * 64;
#pragma unroll
  for (int k = 0; k < 8; ++k) {
    ushort4 a0 = ((const ushort4*)o0)[k * 2];
    ushort4 b0 = ((const ushort4*)o0)[k * 2 + 1];
    ushort4 a1 = ((const ushort4*)o1)[k * 2];
    ushort4 b1 = ((const ushort4*)o1)[k * 2 + 1];
    ushort4 ra, rb;
    ra.x = f2bf(bf2f(a0.x) * w0 + bf2f(a1.x) * w1);
    ra.y = f2bf(bf2f(a0.y) * w0 + bf2f(a1.y) * w1);
    ra.z = f2bf(bf2f(a0.z) * w0 + bf2f(a1.z) * w1);
    ra.w = f2bf(bf2f(a0.w) * w0 + bf2f(a1.w) * w1);
    rb.x = f2bf(bf2f(b0.x) * w0 + bf2f(b1.x) * w1);
    rb.y = f2bf(bf2f(b0.y) * w0 + bf2f(b1.y) * w1);
    rb.z = f2bf(bf2f(b0.z) * w0 + bf2f(b1.z) * w1);
    rb.w = f2bf(bf2f(b0.w) * w0 + bf2f(b1.w) * w1);
    ((ushort4*)op)[k * 2] = ra;
    ((ushort4*)op)[k * 2 + 1] = rb;
  }
}

// ---------------- launch ----------------
extern "C" void kernel_launch(void* const* d_in, const int* in_sizes, int n_in,
                              void* d_out, int out_size, void* d_ws, size_t ws_size,
                              hipStream_t stream) {
  (void)in_sizes; (void)n_in; (void)out_size; (void)ws_size;
  const float* hs = (const float*)d_in[0];
  // d_in[1] = mask (causality is computed analytically)
  const float* Wq = (const float*)d_in[2];
  const float* bq = (const float*)d_in[3];
  const float* Wk = (const float*)d_in[4];
  const float* bk = (const float*)d_in[5];
  const float* Wv = (const float*)d_in[6];
  const float* bv = (const float*)d_in[7];
  const float* Wo = (const float*)d_in[8];
  const float* bo = (const float*)d_in[9];
  float* out = (float*)d_out;

  char* ws = (char*)d_ws;
  u16* Xbf   = (u16*)(ws + 0);          // 16.8 MB
  u16* Wqt   = (u16*)(ws + 16777216);   // 8.4 MB (pi-permuted rows)
  u16* Wkt   = (u16*)(ws + 25165824);   // 2.1 MB (pi-permuted rows)
  u16* Wvt   = (u16*)(ws + 27262976);   // 2.1 MB
  u16* Wot   = (u16*)(ws + 29360128);   // 8.4 MB
  // Qf/Kf fp32 intermediates eliminated (rope fused into QKV GEMM).
  float* Vf  = (float*)(ws + 79691776); // 8.4 MB
  u16* Qbf   = (u16*)(ws + 88080384);   // 16.8 MB
  u16* Kbf   = (u16*)(ws + 104857600);  // 4.2 MB
  u16* Vtb   = (u16*)(ws + 109051904);  // 4.2 MB (+16B pad slack follows)
  u16* attnb = (u16*)(ws + 37748736);   // old Qf region (free)
  float* pML = (float*)(ws + 54525952); // old Qf region (512 slots x 256 f32)
  u16* pO    = (u16*)(ws + 71303168);   // old Kf region + Vf tail... 512 x 32KB:
                                        // spans 71.3M..88.1M; Vf (79.7M..88.1M)
                                        // is dead after k_vtrans, pO written in
                                        // k_attn (after vtrans) — same as r0.

  k_convert<<<8192, 256, 0, stream>>>(hs, Xbf, 2097152);
  k_transpose_w<<<dim3(32, 32), 256, 0, stream>>>(Wq, Wqt, 2048, 2048, 1);
  k_transpose_w<<<dim3(32, 8), 256, 0, stream>>>(Wk, Wkt, 2048, 512, 1);
  k_transpose_w<<<dim3(32, 8), 256, 0, stream>>>(Wv, Wvt, 2048, 512, 0);
  k_transpose_w<<<dim3(32, 32), 256, 0, stream>>>(Wo, Wot, 2048, 2048, 0);
  k_gemm_qkv_fused<<<dim3(32, 24), 256, 0, stream>>>(
      Xbf, Wqt, Wkt, Wvt, bq, bk, bv, Qbf, Kbf, out + 8388608, Vf);
  k_vtrans<<<dim3(32, 2, 8), 256, 0, stream>>>(Vf, Vtb, out + 10485760);
  k_attn<<<dim3(32, 24), 256, 0, stream>>>(Qbf, Kbf, Vtb, attnb, pO, pML);
  k_attn_combine<<<dim3(32, 8), 256, 0, stream>>>(pO, pML, attnb);
  k_gemm_o<<<dim3(32, 16), 256, 0, stream>>>(attnb, Wot, bo, out);
}

// Round 6
// 378.711 us; speedup vs baseline: 1.0563x; 1.0563x over previous
//
#include <hip/hip_runtime.h>
#include <stdint.h>

#define S_LEN 2048
#define HDIM  2048
#define N_HEADS 16
#define HEAD_D 128
#define N_KV 4

typedef unsigned short u16;
typedef __attribute__((ext_vector_type(8))) short bf16x8;
typedef __attribute__((ext_vector_type(4))) short bf16x4;
typedef __attribute__((ext_vector_type(4))) float f32x4;

// K=16 bf16 MFMA (v_mfma_f32_16x16x16_bf16, 2 A-regs = bf16x4 operands).
#define MFMA_PV(a, b, c) __builtin_amdgcn_mfma_f32_16x16x16bf16_1k(a, b, c, 0, 0, 0)

__device__ __forceinline__ u16 f2bf(float f) {
  unsigned u = __float_as_uint(f);
  u += 0x7FFFu + ((u >> 16) & 1u);
  return (u16)(u >> 16);
}

__device__ __forceinline__ float bf2f(u16 v) {
  return __uint_as_float(((unsigned)v) << 16);
}

__device__ __forceinline__ void gll16(void* lds, const void* gp) {
  __builtin_amdgcn_global_load_lds(
      (const __attribute__((address_space(1))) void*)gp,
      (__attribute__((address_space(3))) void*)lds, 16, 0, 0);
}

// ---------------- fp32 -> bf16 convert (vectorized) ----------------
__global__ __launch_bounds__(256) void k_convert(const float* __restrict__ src,
                                                 u16* __restrict__ dst, int n4) {
  int i = blockIdx.x * 256 + threadIdx.x;
  if (i < n4) {
    float4 v = ((const float4*)src)[i];
    ushort4 o;
    o.x = f2bf(v.x); o.y = f2bf(v.y); o.z = f2bf(v.z); o.w = f2bf(v.w);
    ((ushort4*)dst)[i] = o;
  }
}

// ---------------- RoPE trig table: tab[s*64+d1] = (cos, sin) ----------------
// 2048 x 64 float2 = 1 MB, L2-resident. 131k sincosf at FULL occupancy (the
// OCML large-arg slow path is hidden by TLP here; r5 measured that the same
// 5.2M calls inside the GEMM epilogue cost ~70 us of exposed latency).
__global__ __launch_bounds__(256) void k_trig(float2* __restrict__ tab) {
  const float c1 = -13.287712379549449f / 64.f; // -log2(10000)/64
  int idx = blockIdx.x * 256 + threadIdx.x;     // [0, 131072)
  int s = idx >> 6, d1 = idx & 63;
  float fr = exp2f((float)d1 * c1);
  float sn, cs;
  sincosf((float)s * fr, &sn, &cs);
  tab[idx] = make_float2(cs, sn);
}

// ---------------- W [K][N] fp32 -> Wt [N][K] bf16 ----------------
// perm!=0: remap output row within each 128-col head block by
// pi(d) = (d&15) | ((d&48)<<1) | ((d&64)>>2). This puts rope partners
// (d, d+64) at cols (c, c+16) so the fused GEMM epilogue holds both in
// adjacent acc fragments (j=2jp, 2jp+1). Inverse (epilogue side):
// d = (c&15) + ((c>>5)<<4) + ((c&16)<<2).
__global__ __launch_bounds__(256) void k_transpose_w(const float* __restrict__ W,
                                                     u16* __restrict__ Wt,
                                                     int K, int N, int perm) {
  __shared__ float tile[64][65];
  int k0 = blockIdx.x * 64, n0 = blockIdx.y * 64;
  int tr = threadIdx.x >> 6, tc = threadIdx.x & 63;
#pragma unroll
  for (int i = 0; i < 16; ++i) {
    int r = tr + i * 4;
    tile[r][tc] = W[(size_t)(k0 + r) * N + n0 + tc];
  }
  __syncthreads();
#pragma unroll
  for (int i = 0; i < 16; ++i) {
    int r = tr + i * 4;  // n offset
    int nn = n0 + r;
    if (perm)
      nn = (nn & ~127) | ((nn & 15) | ((nn & 48) << 1) | ((nn & 64) >> 2));
    Wt[(size_t)nn * K + k0 + tc] = f2bf(tile[tc][r]);
  }
}

// ---------------- 128x128 bf16 MFMA GEMM mainloop (A[M][K], Bt[N][K]) ----------------
__device__ __forceinline__ void gemm_main_128(
    const u16* __restrict__ A, const u16* __restrict__ Bt,
    int m0, int n0, int K, f32x4 (&acc)[4][4]) {
  __shared__ __align__(16) u16 sA[128 * 32];
  __shared__ __align__(16) u16 sB[128 * 32];
  const int tid = threadIdx.x;
  const int lane = tid & 63;
  const int wave = tid >> 6;
  const int quad = lane >> 4;
  const int l15 = lane & 15;
  const int wm = (wave >> 1) << 6;
  const int wn = (wave & 1) << 6;

#pragma unroll
  for (int i = 0; i < 4; ++i)
#pragma unroll
    for (int j = 0; j < 4; ++j)
      acc[i][j] = (f32x4){0.f, 0.f, 0.f, 0.f};

  for (int kk = 0; kk < K; kk += 32) {
    __syncthreads();
#pragma unroll
    for (int it = 0; it < 2; ++it) {
      int c = tid + (it << 8);     // 512 chunks of 16B per tile
      int row = c >> 2;
      int ko = (c & 3) << 3;
      gll16((char*)sA + c * 16, A + (size_t)(m0 + row) * K + kk + ko);
      gll16((char*)sB + c * 16, Bt + (size_t)(n0 + row) * K + kk + ko);
    }
    __syncthreads();
    bf16x8 af[4], bfr[4];
#pragma unroll
    for (int i = 0; i < 4; ++i)
      af[i] = *(const bf16x8*)&sA[(wm + (i << 4) + l15) * 32 + quad * 8];
#pragma unroll
    for (int j = 0; j < 4; ++j)
      bfr[j] = *(const bf16x8*)&sB[(wn + (j << 4) + l15) * 32 + quad * 8];
#pragma unroll
    for (int i = 0; i < 4; ++i)
#pragma unroll
      for (int j = 0; j < 4; ++j)
        acc[i][j] = __builtin_amdgcn_mfma_f32_16x16x32_bf16(af[i], bfr[j], acc[i][j], 0, 0, 0);
  }
}

// mainloop + standard fp32 epilogue (used by k_gemm_o)
__device__ __forceinline__ void gemm_tile_128(
    const u16* __restrict__ A, const u16* __restrict__ Bt,
    const float* __restrict__ bias, float* __restrict__ C,
    int m0, int n0, int K, int ldc) {
  const int tid = threadIdx.x;
  const int lane = tid & 63;
  const int wave = tid >> 6;
  const int quad = lane >> 4;
  const int l15 = lane & 15;
  const int wm = (wave >> 1) << 6;
  const int wn = (wave & 1) << 6;

  f32x4 acc[4][4];
  gemm_main_128(A, Bt, m0, n0, K, acc);

#pragma unroll
  for (int i = 0; i < 4; ++i) {
    int row = m0 + wm + (i << 4) + quad * 4;
#pragma unroll
    for (int j = 0; j < 4; ++j) {
      int col = n0 + wn + (j << 4) + l15;
      float bv = bias[col];
      float* cp = C + (size_t)row * ldc + col;
#pragma unroll
      for (int r = 0; r < 4; ++r)
        cp[(size_t)r * ldc] = acc[i][j][r] + bv;
    }
  }
}

// ---------------- QKV GEMM with fused RoPE epilogue for Q/K ----------------
// Wqt/Wkt rows are pi-permuted (see k_transpose_w), so thread fragment pair
// (j=2jp, j=2jp+1) holds rope partners (d1, d1+64) with
// d1 = ((wn>>5)+jp)*16 + l15 in [0,64). RoPE uses the PRECOMPUTED trig table
// (r5 lesson: in-epilogue sincosf = OCML large-arg slow path with no TLP to
// hide it, +70 us). Writes Qbf bf16 / Kbf bf16 + past_key fp32 directly.
__global__ __launch_bounds__(256) void k_gemm_qkv_fused(
    const u16* __restrict__ X, const u16* __restrict__ Wqt,
    const u16* __restrict__ Wkt, const u16* __restrict__ Wvt,
    const float* __restrict__ bq, const float* __restrict__ bk,
    const float* __restrict__ bv, u16* __restrict__ Qbf,
    u16* __restrict__ Kbf, float* __restrict__ outK,
    float* __restrict__ Vf, const float2* __restrict__ trig) {
  const int m0 = blockIdx.x << 7;
  const int by = blockIdx.y;
  const int tid = threadIdx.x;
  const int lane = tid & 63;
  const int wave = tid >> 6;
  const int quad = lane >> 4;
  const int l15 = lane & 15;
  const int wm = (wave >> 1) << 6;
  const int wn = (wave & 1) << 6;

  const u16* Bt; int n0;
  if (by < 16)      { Bt = Wqt; n0 = by << 7; }
  else if (by < 20) { Bt = Wkt; n0 = (by - 16) << 7; }
  else              { Bt = Wvt; n0 = (by - 20) << 7; }

  f32x4 acc[4][4];
  gemm_main_128(X, Bt, m0, n0, 2048, acc);

  if (by < 16) {
    // Q: rope + fold 1/sqrt(128)*log2(e), write bf16 [b,h,s,d]
    const float qscale = 0.08838834764831845f * 1.4426950408889634f;
    const int h = by;
#pragma unroll
    for (int jp = 0; jp < 2; ++jp) {
      const int d1 = (((wn >> 5) + jp) << 4) + l15;   // 0..63
      const float b1 = bq[h * 128 + d1];
      const float b2 = bq[h * 128 + d1 + 64];
#pragma unroll
      for (int i = 0; i < 4; ++i) {
        const int rowb = m0 + wm + (i << 4) + quad * 4;
#pragma unroll
        for (int r = 0; r < 4; ++r) {
          const int tok = rowb + r;
          const int b = tok >> 11, s = tok & 2047;
          const float2 t = trig[(s << 6) + d1];       // (cos, sin)
          float x1 = acc[i][2 * jp][r] + b1;
          float x2 = acc[i][2 * jp + 1][r] + b2;
          u16* dst = Qbf + ((size_t)(b * N_HEADS + h) * S_LEN + s) * HEAD_D + d1;
          dst[0]  = f2bf((x1 * t.x - x2 * t.y) * qscale);
          dst[64] = f2bf((x1 * t.y + x2 * t.x) * qscale);
        }
      }
    }
  } else if (by < 20) {
    // K: rope, write bf16 [b,kvh,s,d] + past_key fp32
    const int kvh = by - 16;
#pragma unroll
    for (int jp = 0; jp < 2; ++jp) {
      const int d1 = (((wn >> 5) + jp) << 4) + l15;
      const float b1 = bk[kvh * 128 + d1];
      const float b2 = bk[kvh * 128 + d1 + 64];
#pragma unroll
      for (int i = 0; i < 4; ++i) {
        const int rowb = m0 + wm + (i << 4) + quad * 4;
#pragma unroll
        for (int r = 0; r < 4; ++r) {
          const int tok = rowb + r;
          const int b = tok >> 11, s = tok & 2047;
          const float2 t = trig[(s << 6) + d1];
          float x1 = acc[i][2 * jp][r] + b1;
          float x2 = acc[i][2 * jp + 1][r] + b2;
          float o1 = x1 * t.x - x2 * t.y;
          float o2 = x1 * t.y + x2 * t.x;
          size_t idx = ((size_t)(b * N_KV + kvh) * S_LEN + s) * HEAD_D + d1;
          Kbf[idx]      = f2bf(o1);
          Kbf[idx + 64] = f2bf(o2);
          outK[idx]      = o1;
          outK[idx + 64] = o2;
        }
      }
    }
  } else {
    // V: standard fp32 epilogue -> Vf [b*s][512]
#pragma unroll
    for (int i = 0; i < 4; ++i) {
      int row = m0 + wm + (i << 4) + quad * 4;
#pragma unroll
      for (int j = 0; j < 4; ++j) {
        int col = n0 + wn + (j << 4) + l15;
        float bvv = bv[col];
        float* cp = Vf + (size_t)row * 512 + col;
#pragma unroll
        for (int r = 0; r < 4; ++r)
          cp[(size_t)r * 512] = acc[i][j][r] + bvv;
      }
    }
  }
}

__global__ __launch_bounds__(256) void k_gemm_o(
    const u16* __restrict__ A, const u16* __restrict__ Wot,
    const float* __restrict__ bo, float* __restrict__ C) {
  gemm_tile_128(A, Wot, bo, C, blockIdx.x << 7, blockIdx.y << 7, 2048, 2048);
}

// ---------------- V: Vf fp32 [b,s,kvh*d] -> Vt bf16 [b,kvh,d,s] + past_value fp32 ----------------
__global__ __launch_bounds__(256) void k_vtrans(const float* __restrict__ Vf,
                                                u16* __restrict__ Vt,
                                                float* __restrict__ outV) {
  __shared__ float tile[64][65];
  int s0 = blockIdx.x * 64, d0 = blockIdx.y * 64;
  int z = blockIdx.z;                 // b*N_KV + kvh
  int b = z >> 2, kvh = z & 3;
  int tr = threadIdx.x >> 6, tc = threadIdx.x & 63;
#pragma unroll
  for (int i = 0; i < 16; ++i) {
    int r = tr + i * 4;   // s offset
    float v = Vf[(size_t)(b * S_LEN + s0 + r) * 512 + kvh * 128 + d0 + tc];
    tile[r][tc] = v;
    outV[((size_t)z * S_LEN + s0 + r) * HEAD_D + d0 + tc] = v;
  }
  __syncthreads();
#pragma unroll
  for (int i = 0; i < 16; ++i) {
    int r = tr + i * 4;   // d offset
    Vt[((size_t)z * HEAD_D + d0 + r) * S_LEN + s0 + tc] = f2bf(tile[tc][r]);
  }
}

// ---------------- flash attention, S^T formulation, split-KV ----------------
// Round-0 form verbatim (84.5 us measured). r1-r4 established: (256,3)
// spills 211 MB (175 us); plain (256) floats to 172 VGPR / 2 waves-SIMD
// (123 us); constant-sum decode is -4% (LPT heavy-first wins); dbuf+counted
// vmcnt is -7% (2-blocks/CU already hides staging). (256,2) is the sweet spot.
__global__ __launch_bounds__(256, 2) void k_attn(
    const u16* __restrict__ Qbf, const u16* __restrict__ Kbf,
    const u16* __restrict__ Vt, u16* __restrict__ attn,
    u16* __restrict__ pO, float* __restrict__ pML) {
  __shared__ __align__(16) u16 smem[17920];   // 35840 B
  u16* sK = smem;            // 64 x 136  (8704)
  u16* sV = smem + 8704;     // 128 x 72  (9216)

  const int tid = threadIdx.x;
  const int lane = tid & 63;
  const int wave = tid >> 6;
  const int quad = lane >> 4;
  const int l15 = lane & 15;

  const int by = blockIdx.y;
  int qt, t0, t1, slot;
  bool finalw;
  if (by < 8) {               // heavy chunk0: 16 tiles, below-diagonal only
    qt = 8 + by; t0 = 0; t1 = 16; finalw = false;
    slot = ((blockIdx.x << 3) + (qt - 8)) << 1;
  } else {
    qt = 23 - by;
    if (qt >= 8) {            // heavy chunk1: diagonal part
      t0 = 16; t1 = 2 * qt + 2; finalw = false;
      slot = (((blockIdx.x << 3) + (qt - 8)) << 1) + 1;
    } else {                  // light q-tile: whole row, direct final write
      t0 = 0; t1 = 2 * qt + 2; finalw = true; slot = 0;
    }
  }

  const int bh = blockIdx.x;
  const int b = bh >> 4;
  const int h = bh & 15;
  const int kvh = h >> 2;
  const int q0 = qt << 7;
  const int qw = q0 + wave * 32;      // this wave's first q row

  const u16* Qb = Qbf + ((size_t)(b * N_HEADS + h) * S_LEN + qw) * HEAD_D;
  const u16* Kb = Kbf + (size_t)(b * N_KV + kvh) * S_LEN * HEAD_D;
  const u16* Vb = Vt + (size_t)(b * N_KV + kvh) * HEAD_D * S_LEN;

  // Q fragments (B-operand: lane holds Q[q=l15][d=quad*8+j]) for 2 row-groups
  bf16x8 aq[2][4];
#pragma unroll
  for (int i = 0; i < 2; ++i)
#pragma unroll
    for (int kc = 0; kc < 4; ++kc)
      aq[i][kc] = *(const bf16x8*)(Qb + (size_t)(i * 16 + l15) * HEAD_D + kc * 32 + quad * 8);

  float mst[2] = {-1e30f, -1e30f}, lst[2] = {0.f, 0.f};
  f32x4 oacc[2][8];
#pragma unroll
  for (int i = 0; i < 2; ++i)
#pragma unroll
    for (int n = 0; n < 8; ++n) oacc[i][n] = (f32x4){0.f, 0.f, 0.f, 0.f};

  for (int t = t0; t < t1; ++t) {
    const int kt0 = t << 6;
    __syncthreads();
    // stage K (64x17 chunks = 1088) + V (128x9 = 1152)
#pragma unroll
    for (int it = 0; it < 9; ++it) {
      int c = tid + (it << 8);
      if (c < 1088) {
        int row = c / 17;
        int k16 = c - row * 17;
        gll16((char*)sK + c * 16, Kb + (size_t)(kt0 + row) * HEAD_D + k16 * 8);
      } else if (c < 2240) {
        int vv = c - 1088;
        int d = vv / 9;
        int s16 = vv - d * 9;
        gll16((char*)sV + vv * 16, Vb + (size_t)d * S_LEN + kt0 + s16 * 8);
      }
    }
    __syncthreads();

    if (kt0 > qw + 31) continue;      // fully-masked for this wave (uniform branch)

    // S^T = K * Q^T : lane holds S[q=l15][s=quad*4+r] per 16x16 j-tile
    f32x4 st[2][4];
#pragma unroll
    for (int i = 0; i < 2; ++i)
#pragma unroll
      for (int j = 0; j < 4; ++j) st[i][j] = (f32x4){0.f, 0.f, 0.f, 0.f};
#pragma unroll
    for (int kc = 0; kc < 4; ++kc) {
#pragma unroll
      for (int j = 0; j < 4; ++j) {
        bf16x8 kf = *(const bf16x8*)&sK[(j * 16 + l15) * 136 + kc * 32 + quad * 8];
#pragma unroll
        for (int i = 0; i < 2; ++i)
          st[i][j] = __builtin_amdgcn_mfma_f32_16x16x32_bf16(kf, aq[i][kc], st[i][j], 0, 0, 0);
      }
    }

    if (kt0 + 63 > qw) {              // diagonal region: causal mask
#pragma unroll
      for (int i = 0; i < 2; ++i) {
        int q = qw + i * 16 + l15;
#pragma unroll
        for (int j = 0; j < 4; ++j) {
          int s = kt0 + j * 16 + quad * 4;
#pragma unroll
          for (int r = 0; r < 4; ++r)
            if (s + r > q) st[i][j][r] = -1e9f;
        }
      }
    }

    // online softmax; row stats live per-lane (q=l15), replicated across quads
    bf16x4 pf[2][4];
    float al[2];
#pragma unroll
    for (int i = 0; i < 2; ++i) {
      float m = -1e30f;
#pragma unroll
      for (int j = 0; j < 4; ++j)
#pragma unroll
        for (int r = 0; r < 4; ++r) m = fmaxf(m, st[i][j][r]);
      m = fmaxf(m, __shfl_xor(m, 16, 64));
      m = fmaxf(m, __shfl_xor(m, 32, 64));
      float mn = fmaxf(mst[i], m);
      al[i] = exp2f(mst[i] - mn);
      mst[i] = mn;
      float rs = 0.f;
#pragma unroll
      for (int j = 0; j < 4; ++j) {
        float p0 = exp2f(st[i][j][0] - mn);
        float p1 = exp2f(st[i][j][1] - mn);
        float p2 = exp2f(st[i][j][2] - mn);
        float p3 = exp2f(st[i][j][3] - mn);
        rs += (p0 + p1) + (p2 + p3);
        // pack 4 fp32 -> 4 bf16 via v_perm (half-up rounding)
        union { unsigned u[2]; bf16x4 v; } pk;
        pk.u[0] = __builtin_amdgcn_perm(__float_as_uint(p1) + 0x8000u,
                                        __float_as_uint(p0) + 0x8000u, 0x07060302u);
        pk.u[1] = __builtin_amdgcn_perm(__float_as_uint(p3) + 0x8000u,
                                        __float_as_uint(p2) + 0x8000u, 0x07060302u);
        pf[i][j] = pk.v;
      }
      rs += __shfl_xor(rs, 16, 64);
      rs += __shfl_xor(rs, 32, 64);
      lst[i] = lst[i] * al[i] + rs;
      // rescale O: rows of oacc are q=quad*4+r, fetch al for that row
#pragma unroll
      for (int r = 0; r < 4; ++r) {
        float a = __shfl(al[i], quad * 4 + r, 16);
#pragma unroll
        for (int n = 0; n < 8; ++n) oacc[i][n][r] *= a;
      }
    }

    // O += P*V via K=16 MFMA; P is already in A-layout in registers
#pragma unroll
    for (int j = 0; j < 4; ++j) {
#pragma unroll
      for (int n = 0; n < 8; ++n) {
        bf16x4 vf = *(const bf16x4*)&sV[(n * 16 + l15) * 72 + j * 16 + quad * 4];
#pragma unroll
        for (int i = 0; i < 2; ++i)
          oacc[i][n] = MFMA_PV(pf[i][j], vf, oacc[i][n]);
      }
    }
  }

  if (finalw) {
    // normalize + write [b, s, h, d] bf16 for the O-projection
#pragma unroll
    for (int i = 0; i < 2; ++i)
#pragma unroll
      for (int r = 0; r < 4; ++r) {
        float inv = 1.0f / __shfl(lst[i], quad * 4 + r, 16);
        int row = qw + i * 16 + quad * 4 + r;
        u16* op = attn + ((size_t)b * S_LEN + row) * HDIM + h * HEAD_D;
#pragma unroll
        for (int n = 0; n < 8; ++n)
          op[n * 16 + l15] = f2bf(oacc[i][n][r] * inv);
      }
  } else {
    // unnormalized partial O (bf16) + per-row m,l
    u16* po = pO + (size_t)slot * 16384;
#pragma unroll
    for (int i = 0; i < 2; ++i)
#pragma unroll
      for (int r = 0; r < 4; ++r) {
        int row = wave * 32 + i * 16 + quad * 4 + r;
#pragma unroll
        for (int n = 0; n < 8; ++n)
          po[row * 128 + n * 16 + l15] = f2bf(oacc[i][n][r]);
      }
    if (quad == 0) {
      float* ml = pML + slot * 256;
#pragma unroll
      for (int i = 0; i < 2; ++i) {
        int row = wave * 32 + i * 16 + l15;
        ml[row] = mst[i];
        ml[128 + row] = lst[i];
      }
    }
  }
}

// ---------------- combine the two partials of each heavy q-tile ----------------
__global__ __launch_bounds__(256) void k_attn_combine(
    const u16* __restrict__ pO, const float* __restrict__ pML,
    u16* __restrict__ attn) {
  const int bh = blockIdx.x;          // b*16 + h
  const int qt = 8 + blockIdx.y;
  const int b = bh >> 4;
  const int h = bh & 15;
  const int s0 = ((bh << 3) + blockIdx.y) << 1;   // slot pair base
  const int row = threadIdx.x >> 1;               // 0..127
  const int half = threadIdx.x & 1;               // 0..1 (64 cols each)

  const float* ml0 = pML + s0 * 256;
  const float* ml1 = pML + (s0 + 1) * 256;
  float m0 = ml0[row], l0 = ml0[128 + row];
  float m1 = ml1[row], l1 = ml1[128 + row];
  float m = fmaxf(m0, m1);
  float w0 = exp2f(m0 - m), w1 = exp2f(m1 - m);
  float inv = 1.0f / (l0 * w0 + l1 * w1);
  w0 *= inv; w1 *= inv;

  const u16* o0 = pO + (size_t)s0 * 16384 + row * 128 + half * 64;
  const u16* o1 = o0 + 16384;
  u16* op = attn + ((size_t)(b * S_LEN + (qt << 7) + row)) * HDIM + h * HEAD_D + half * 64;
#pragma unroll
  for (int k = 0; k < 8; ++k) {
    ushort4 a0 = ((const ushort4*)o0)[k * 2];
    ushort4 b0 = ((const ushort4*)o0)[k * 2 + 1];
    ushort4 a1 = ((const ushort4*)o1)[k * 2];
    ushort4 b1 = ((const ushort4*)o1)[k * 2 + 1];
    ushort4 ra, rb;
    ra.x = f2bf(bf2f(a0.x) * w0 + bf2f(a1.x) * w1);
    ra.y = f2bf(bf2f(a0.y) * w0 + bf2f(a1.y) * w1);
    ra.z = f2bf(bf2f(a0.z) * w0 + bf2f(a1.z) * w1);
    ra.w = f2bf(bf2f(a0.w) * w0 + bf2f(a1.w) * w1);
    rb.x = f2bf(bf2f(b0.x) * w0 + bf2f(b1.x) * w1);
    rb.y = f2bf(bf2f(b0.y) * w0 + bf2f(b1.y) * w1);
    rb.z = f2bf(bf2f(b0.z) * w0 + bf2f(b1.z) * w1);
    rb.w = f2bf(bf2f(b0.w) * w0 + bf2f(b1.w) * w1);
    ((ushort4*)op)[k * 2] = ra;
    ((ushort4*)op)[k * 2 + 1] = rb;
  }
}

// ---------------- launch ----------------
extern "C" void kernel_launch(void* const* d_in, const int* in_sizes, int n_in,
                              void* d_out, int out_size, void* d_ws, size_t ws_size,
                              hipStream_t stream) {
  (void)in_sizes; (void)n_in; (void)out_size; (void)ws_size;
  const float* hs = (const float*)d_in[0];
  // d_in[1] = mask (causality is computed analytically)
  const float* Wq = (const float*)d_in[2];
  const float* bq = (const float*)d_in[3];
  const float* Wk = (const float*)d_in[4];
  const float* bk = (const float*)d_in[5];
  const float* Wv = (const float*)d_in[6];
  const float* bv = (const float*)d_in[7];
  const float* Wo = (const float*)d_in[8];
  const float* bo = (const float*)d_in[9];
  float* out = (float*)d_out;

  char* ws = (char*)d_ws;
  u16* Xbf   = (u16*)(ws + 0);          // 16.8 MB
  u16* Wqt   = (u16*)(ws + 16777216);   // 8.4 MB (pi-permuted rows)
  u16* Wkt   = (u16*)(ws + 25165824);   // 2.1 MB (pi-permuted rows)
  u16* Wvt   = (u16*)(ws + 27262976);   // 2.1 MB
  u16* Wot   = (u16*)(ws + 29360128);   // 8.4 MB
  float* Vf  = (float*)(ws + 79691776); // 8.4 MB
  u16* Qbf   = (u16*)(ws + 88080384);   // 16.8 MB
  u16* Kbf   = (u16*)(ws + 104857600);  // 4.2 MB
  u16* Vtb   = (u16*)(ws + 109051904);  // 4.2 MB (+16B pad slack follows)
  u16* attnb = (u16*)(ws + 37748736);   // old Qf region (free until k_attn)
  float* pML = (float*)(ws + 54525952); // 512 slots x 256 f32 (0.5 MB)
  float2* trg = (float2*)(ws + 56623104); // 1 MB trig table (free gap 55.1-71.3MB)
  u16* pO    = (u16*)(ws + 71303168);   // 512 x 32KB (written in k_attn;
                                        // Vf region is dead by then)

  k_trig<<<512, 256, 0, stream>>>(trg);
  k_convert<<<8192, 256, 0, stream>>>(hs, Xbf, 2097152);
  k_transpose_w<<<dim3(32, 32), 256, 0, stream>>>(Wq, Wqt, 2048, 2048, 1);
  k_transpose_w<<<dim3(32, 8), 256, 0, stream>>>(Wk, Wkt, 2048, 512, 1);
  k_transpose_w<<<dim3(32, 8), 256, 0, stream>>>(Wv, Wvt, 2048, 512, 0);
  k_transpose_w<<<dim3(32, 32), 256, 0, stream>>>(Wo, Wot, 2048, 2048, 0);
  k_gemm_qkv_fused<<<dim3(32, 24), 256, 0, stream>>>(
      Xbf, Wqt, Wkt, Wvt, bq, bk, bv, Qbf, Kbf, out + 8388608, Vf, trg);
  k_vtrans<<<dim3(32, 2, 8), 256, 0, stream>>>(Vf, Vtb, out + 10485760);
  k_attn<<<dim3(32, 24), 256, 0, stream>>>(Qbf, Kbf, Vtb, attnb, pO, pML);
  k_attn_combine<<<dim3(32, 8), 256, 0, stream>>>(pO, pML, attnb);
  k_gemm_o<<<dim3(32, 16), 256, 0, stream>>>(attnb, Wot, bo, out);
}

// Round 7
// 365.431 us; speedup vs baseline: 1.0947x; 1.0363x over previous
//
#include <hip/hip_runtime.h>
#include <stdint.h>

#define S_LEN 2048
#define HDIM  2048
#define N_HEADS 16
#define HEAD_D 128
#define N_KV 4

typedef unsigned short u16;
typedef __attribute__((ext_vector_type(8))) short bf16x8;
typedef __attribute__((ext_vector_type(4))) short bf16x4;
typedef __attribute__((ext_vector_type(4))) float f32x4;

// K=16 bf16 MFMA (v_mfma_f32_16x16x16_bf16, 2 A-regs = bf16x4 operands).
#define MFMA_PV(a, b, c) __builtin_amdgcn_mfma_f32_16x16x16bf16_1k(a, b, c, 0, 0, 0)

__device__ __forceinline__ u16 f2bf(float f) {
  unsigned u = __float_as_uint(f);
  u += 0x7FFFu + ((u >> 16) & 1u);
  return (u16)(u >> 16);
}

__device__ __forceinline__ float bf2f(u16 v) {
  return __uint_as_float(((unsigned)v) << 16);
}

__device__ __forceinline__ void gll16(void* lds, const void* gp) {
  __builtin_amdgcn_global_load_lds(
      (const __attribute__((address_space(1))) void*)gp,
      (__attribute__((address_space(3))) void*)lds, 16, 0, 0);
}

// ---------------- fused prep: convert + 4x weight transpose + trig table ----------------
// Replaces 6 launches with 1 (r6 lesson: ~110 us of wall time was
// inter-dispatch gap on an 11-launch serial stream).
// Block ranges: [0,8192) convert; [8192,9216) Wq; [9216,9472) Wk;
// [9472,9728) Wv; [9728,10752) Wo; [10752,11264) trig.
// perm!=0 on Wq/Wk: remap output row within each 128-col head block by
// pi(d) = (d&15) | ((d&48)<<1) | ((d&64)>>2) so rope partners (d, d+64)
// land in adjacent acc fragments of the fused GEMM epilogue.
__device__ __forceinline__ void wtrans_body(
    const float* __restrict__ W, u16* __restrict__ Wt, int K, int N,
    int perm, int flat, float (*tile)[65]) {
  int k0 = (flat & 31) * 64, n0 = (flat >> 5) * 64;
  int tr = threadIdx.x >> 6, tc = threadIdx.x & 63;
#pragma unroll
  for (int i = 0; i < 16; ++i) {
    int r = tr + i * 4;
    tile[r][tc] = W[(size_t)(k0 + r) * N + n0 + tc];
  }
  __syncthreads();
#pragma unroll
  for (int i = 0; i < 16; ++i) {
    int r = tr + i * 4;  // n offset
    int nn = n0 + r;
    if (perm)
      nn = (nn & ~127) | ((nn & 15) | ((nn & 48) << 1) | ((nn & 64) >> 2));
    Wt[(size_t)nn * K + k0 + tc] = f2bf(tile[tc][r]);
  }
}

__global__ __launch_bounds__(256) void k_prep(
    const float* __restrict__ hs, u16* __restrict__ Xbf,
    const float* __restrict__ Wq, u16* __restrict__ Wqt,
    const float* __restrict__ Wk, u16* __restrict__ Wkt,
    const float* __restrict__ Wv, u16* __restrict__ Wvt,
    const float* __restrict__ Wo, u16* __restrict__ Wot,
    float2* __restrict__ trig) {
  __shared__ float tile[64][65];
  const int bid = blockIdx.x;
  if (bid < 8192) {
    // hs fp32 -> Xbf bf16, float4-vectorized (n4 = 2097152)
    int i = bid * 256 + threadIdx.x;
    float4 v = ((const float4*)hs)[i];
    ushort4 o;
    o.x = f2bf(v.x); o.y = f2bf(v.y); o.z = f2bf(v.z); o.w = f2bf(v.w);
    ((ushort4*)Xbf)[i] = o;
  } else if (bid < 9216) {
    wtrans_body(Wq, Wqt, 2048, 2048, 1, bid - 8192, tile);
  } else if (bid < 9472) {
    wtrans_body(Wk, Wkt, 2048, 512, 1, bid - 9216, tile);
  } else if (bid < 9728) {
    wtrans_body(Wv, Wvt, 2048, 512, 0, bid - 9472, tile);
  } else if (bid < 10752) {
    wtrans_body(Wo, Wot, 2048, 2048, 0, bid - 9728, tile);
  } else {
    // RoPE trig table tab[s*64+d1] = (cos, sin); 2048x64 float2 = 1 MB.
    // Full-occupancy sincosf (r5 lesson: in-epilogue sincosf = OCML
    // large-arg slow path with no TLP to hide it, +70 us).
    const float c1 = -13.287712379549449f / 64.f; // -log2(10000)/64
    int idx = (bid - 10752) * 256 + threadIdx.x;  // [0, 131072)
    int s = idx >> 6, d1 = idx & 63;
    float fr = exp2f((float)d1 * c1);
    float sn, cs;
    sincosf((float)s * fr, &sn, &cs);
    trig[idx] = make_float2(cs, sn);
  }
}

// ---------------- 128x128 bf16 MFMA GEMM mainloop (A[M][K], Bt[N][K]) ----------------
__device__ __forceinline__ void gemm_main_128(
    const u16* __restrict__ A, const u16* __restrict__ Bt,
    int m0, int n0, int K, f32x4 (&acc)[4][4]) {
  __shared__ __align__(16) u16 sA[128 * 32];
  __shared__ __align__(16) u16 sB[128 * 32];
  const int tid = threadIdx.x;
  const int lane = tid & 63;
  const int wave = tid >> 6;
  const int quad = lane >> 4;
  const int l15 = lane & 15;
  const int wm = (wave >> 1) << 6;
  const int wn = (wave & 1) << 6;

#pragma unroll
  for (int i = 0; i < 4; ++i)
#pragma unroll
    for (int j = 0; j < 4; ++j)
      acc[i][j] = (f32x4){0.f, 0.f, 0.f, 0.f};

  for (int kk = 0; kk < K; kk += 32) {
    __syncthreads();
#pragma unroll
    for (int it = 0; it < 2; ++it) {
      int c = tid + (it << 8);     // 512 chunks of 16B per tile
      int row = c >> 2;
      int ko = (c & 3) << 3;
      gll16((char*)sA + c * 16, A + (size_t)(m0 + row) * K + kk + ko);
      gll16((char*)sB + c * 16, Bt + (size_t)(n0 + row) * K + kk + ko);
    }
    __syncthreads();
    bf16x8 af[4], bfr[4];
#pragma unroll
    for (int i = 0; i < 4; ++i)
      af[i] = *(const bf16x8*)&sA[(wm + (i << 4) + l15) * 32 + quad * 8];
#pragma unroll
    for (int j = 0; j < 4; ++j)
      bfr[j] = *(const bf16x8*)&sB[(wn + (j << 4) + l15) * 32 + quad * 8];
#pragma unroll
    for (int i = 0; i < 4; ++i)
#pragma unroll
      for (int j = 0; j < 4; ++j)
        acc[i][j] = __builtin_amdgcn_mfma_f32_16x16x32_bf16(af[i], bfr[j], acc[i][j], 0, 0, 0);
  }
}

// mainloop + standard fp32 epilogue (used by k_gemm_o)
__device__ __forceinline__ void gemm_tile_128(
    const u16* __restrict__ A, const u16* __restrict__ Bt,
    const float* __restrict__ bias, float* __restrict__ C,
    int m0, int n0, int K, int ldc) {
  const int tid = threadIdx.x;
  const int lane = tid & 63;
  const int wave = tid >> 6;
  const int quad = lane >> 4;
  const int l15 = lane & 15;
  const int wm = (wave >> 1) << 6;
  const int wn = (wave & 1) << 6;

  f32x4 acc[4][4];
  gemm_main_128(A, Bt, m0, n0, K, acc);

#pragma unroll
  for (int i = 0; i < 4; ++i) {
    int row = m0 + wm + (i << 4) + quad * 4;
#pragma unroll
    for (int j = 0; j < 4; ++j) {
      int col = n0 + wn + (j << 4) + l15;
      float bv = bias[col];
      float* cp = C + (size_t)row * ldc + col;
#pragma unroll
      for (int r = 0; r < 4; ++r)
        cp[(size_t)r * ldc] = acc[i][j][r] + bv;
    }
  }
}

// ---------------- QKV GEMM with fused RoPE (Q/K) + V-transpose epilogues ----------------
// Wqt/Wkt rows are pi-permuted (see k_prep), so thread fragment pair
// (j=2jp, j=2jp+1) holds rope partners (d1, d1+64). RoPE uses the
// precomputed trig table. V branch writes Vt bf16 [b,kvh,d,s] directly
// (ushort4 over the 4 consecutive tokens per acc row — r7: replaces
// k_vtrans) + past_value fp32 [b,kvh,s,d] coalesced.
__global__ __launch_bounds__(256) void k_gemm_qkv_fused(
    const u16* __restrict__ X, const u16* __restrict__ Wqt,
    const u16* __restrict__ Wkt, const u16* __restrict__ Wvt,
    const float* __restrict__ bq, const float* __restrict__ bk,
    const float* __restrict__ bv, u16* __restrict__ Qbf,
    u16* __restrict__ Kbf, float* __restrict__ outK,
    u16* __restrict__ Vt, float* __restrict__ outV,
    const float2* __restrict__ trig) {
  const int m0 = blockIdx.x << 7;
  const int by = blockIdx.y;
  const int tid = threadIdx.x;
  const int lane = tid & 63;
  const int wave = tid >> 6;
  const int quad = lane >> 4;
  const int l15 = lane & 15;
  const int wm = (wave >> 1) << 6;
  const int wn = (wave & 1) << 6;

  const u16* Bt; int n0;
  if (by < 16)      { Bt = Wqt; n0 = by << 7; }
  else if (by < 20) { Bt = Wkt; n0 = (by - 16) << 7; }
  else              { Bt = Wvt; n0 = (by - 20) << 7; }

  f32x4 acc[4][4];
  gemm_main_128(X, Bt, m0, n0, 2048, acc);

  if (by < 16) {
    // Q: rope + fold 1/sqrt(128)*log2(e), write bf16 [b,h,s,d]
    const float qscale = 0.08838834764831845f * 1.4426950408889634f;
    const int h = by;
#pragma unroll
    for (int jp = 0; jp < 2; ++jp) {
      const int d1 = (((wn >> 5) + jp) << 4) + l15;   // 0..63
      const float b1 = bq[h * 128 + d1];
      const float b2 = bq[h * 128 + d1 + 64];
#pragma unroll
      for (int i = 0; i < 4; ++i) {
        const int rowb = m0 + wm + (i << 4) + quad * 4;
#pragma unroll
        for (int r = 0; r < 4; ++r) {
          const int tok = rowb + r;
          const int b = tok >> 11, s = tok & 2047;
          const float2 t = trig[(s << 6) + d1];       // (cos, sin)
          float x1 = acc[i][2 * jp][r] + b1;
          float x2 = acc[i][2 * jp + 1][r] + b2;
          u16* dst = Qbf + ((size_t)(b * N_HEADS + h) * S_LEN + s) * HEAD_D + d1;
          dst[0]  = f2bf((x1 * t.x - x2 * t.y) * qscale);
          dst[64] = f2bf((x1 * t.y + x2 * t.x) * qscale);
        }
      }
    }
  } else if (by < 20) {
    // K: rope, write bf16 [b,kvh,s,d] + past_key fp32
    const int kvh = by - 16;
#pragma unroll
    for (int jp = 0; jp < 2; ++jp) {
      const int d1 = (((wn >> 5) + jp) << 4) + l15;
      const float b1 = bk[kvh * 128 + d1];
      const float b2 = bk[kvh * 128 + d1 + 64];
#pragma unroll
      for (int i = 0; i < 4; ++i) {
        const int rowb = m0 + wm + (i << 4) + quad * 4;
#pragma unroll
        for (int r = 0; r < 4; ++r) {
          const int tok = rowb + r;
          const int b = tok >> 11, s = tok & 2047;
          const float2 t = trig[(s << 6) + d1];
          float x1 = acc[i][2 * jp][r] + b1;
          float x2 = acc[i][2 * jp + 1][r] + b2;
          float o1 = x1 * t.x - x2 * t.y;
          float o2 = x1 * t.y + x2 * t.x;
          size_t idx = ((size_t)(b * N_KV + kvh) * S_LEN + s) * HEAD_D + d1;
          Kbf[idx]      = f2bf(o1);
          Kbf[idx + 64] = f2bf(o2);
          outK[idx]      = o1;
          outK[idx + 64] = o2;
        }
      }
    }
  } else {
    // V: write Vt bf16 [b,kvh,d,s] (transposed, for attn) + past_value fp32.
    // acc rows r=0..3 are 4 consecutive tokens (same batch: rowb%4==0,
    // 2048%4==0) -> one ushort4 store per (i,j) at Vt[z][d][s..s+3].
    const int kvh = by - 20;
#pragma unroll
    for (int i = 0; i < 4; ++i) {
      const int rowb = m0 + wm + (i << 4) + quad * 4;
      const int b = rowb >> 11, s = rowb & 2047;
      const int z = b * N_KV + kvh;
#pragma unroll
      for (int j = 0; j < 4; ++j) {
        const int d = wn + (j << 4) + l15;            // 0..127 within head
        const float bvv = bv[kvh * 128 + d];
        float v0 = acc[i][j][0] + bvv;
        float v1 = acc[i][j][1] + bvv;
        float v2 = acc[i][j][2] + bvv;
        float v3 = acc[i][j][3] + bvv;
        float* ov = outV + ((size_t)z * S_LEN + s) * HEAD_D + d;
        ov[0]   = v0;
        ov[128] = v1;
        ov[256] = v2;
        ov[384] = v3;
        ushort4 pk;
        pk.x = f2bf(v0); pk.y = f2bf(v1); pk.z = f2bf(v2); pk.w = f2bf(v3);
        *(ushort4*)(Vt + ((size_t)z * HEAD_D + d) * S_LEN + s) = pk;
      }
    }
  }
}

__global__ __launch_bounds__(256) void k_gemm_o(
    const u16* __restrict__ A, const u16* __restrict__ Wot,
    const float* __restrict__ bo, float* __restrict__ C) {
  gemm_tile_128(A, Wot, bo, C, blockIdx.x << 7, blockIdx.y << 7, 2048, 2048);
}

// ---------------- flash attention, S^T formulation, split-KV ----------------
// Round-0 form verbatim (84.5 us measured). r1-r4 established: (256,3)
// spills 211 MB (175 us); plain (256) floats to 172 VGPR / 2 waves-SIMD
// (123 us); constant-sum decode is -4% (LPT heavy-first wins); dbuf+counted
// vmcnt is -7% (2-blocks/CU already hides staging). (256,2) is the sweet spot.
__global__ __launch_bounds__(256, 2) void k_attn(
    const u16* __restrict__ Qbf, const u16* __restrict__ Kbf,
    const u16* __restrict__ Vt, u16* __restrict__ attn,
    u16* __restrict__ pO, float* __restrict__ pML) {
  __shared__ __align__(16) u16 smem[17920];   // 35840 B
  u16* sK = smem;            // 64 x 136  (8704)
  u16* sV = smem + 8704;     // 128 x 72  (9216)

  const int tid = threadIdx.x;
  const int lane = tid & 63;
  const int wave = tid >> 6;
  const int quad = lane >> 4;
  const int l15 = lane & 15;

  const int by = blockIdx.y;
  int qt, t0, t1, slot;
  bool finalw;
  if (by < 8) {               // heavy chunk0: 16 tiles, below-diagonal only
    qt = 8 + by; t0 = 0; t1 = 16; finalw = false;
    slot = ((blockIdx.x << 3) + (qt - 8)) << 1;
  } else {
    qt = 23 - by;
    if (qt >= 8) {            // heavy chunk1: diagonal part
      t0 = 16; t1 = 2 * qt + 2; finalw = false;
      slot = (((blockIdx.x << 3) + (qt - 8)) << 1) + 1;
    } else {                  // light q-tile: whole row, direct final write
      t0 = 0; t1 = 2 * qt + 2; finalw = true; slot = 0;
    }
  }

  const int bh = blockIdx.x;
  const int b = bh >> 4;
  const int h = bh & 15;
  const int kvh = h >> 2;
  const int q0 = qt << 7;
  const int qw = q0 + wave * 32;      // this wave's first q row

  const u16* Qb = Qbf + ((size_t)(b * N_HEADS + h) * S_LEN + qw) * HEAD_D;
  const u16* Kb = Kbf + (size_t)(b * N_KV + kvh) * S_LEN * HEAD_D;
  const u16* Vb = Vt + (size_t)(b * N_KV + kvh) * HEAD_D * S_LEN;

  // Q fragments (B-operand: lane holds Q[q=l15][d=quad*8+j]) for 2 row-groups
  bf16x8 aq[2][4];
#pragma unroll
  for (int i = 0; i < 2; ++i)
#pragma unroll
    for (int kc = 0; kc < 4; ++kc)
      aq[i][kc] = *(const bf16x8*)(Qb + (size_t)(i * 16 + l15) * HEAD_D + kc * 32 + quad * 8);

  float mst[2] = {-1e30f, -1e30f}, lst[2] = {0.f, 0.f};
  f32x4 oacc[2][8];
#pragma unroll
  for (int i = 0; i < 2; ++i)
#pragma unroll
    for (int n = 0; n < 8; ++n) oacc[i][n] = (f32x4){0.f, 0.f, 0.f, 0.f};

  for (int t = t0; t < t1; ++t) {
    const int kt0 = t << 6;
    __syncthreads();
    // stage K (64x17 chunks = 1088) + V (128x9 = 1152)
#pragma unroll
    for (int it = 0; it < 9; ++it) {
      int c = tid + (it << 8);
      if (c < 1088) {
        int row = c / 17;
        int k16 = c - row * 17;
        gll16((char*)sK + c * 16, Kb + (size_t)(kt0 + row) * HEAD_D + k16 * 8);
      } else if (c < 2240) {
        int vv = c - 1088;
        int d = vv / 9;
        int s16 = vv - d * 9;
        gll16((char*)sV + vv * 16, Vb + (size_t)d * S_LEN + kt0 + s16 * 8);
      }
    }
    __syncthreads();

    if (kt0 > qw + 31) continue;      // fully-masked for this wave (uniform branch)

    // S^T = K * Q^T : lane holds S[q=l15][s=quad*4+r] per 16x16 j-tile
    f32x4 st[2][4];
#pragma unroll
    for (int i = 0; i < 2; ++i)
#pragma unroll
      for (int j = 0; j < 4; ++j) st[i][j] = (f32x4){0.f, 0.f, 0.f, 0.f};
#pragma unroll
    for (int kc = 0; kc < 4; ++kc) {
#pragma unroll
      for (int j = 0; j < 4; ++j) {
        bf16x8 kf = *(const bf16x8*)&sK[(j * 16 + l15) * 136 + kc * 32 + quad * 8];
#pragma unroll
        for (int i = 0; i < 2; ++i)
          st[i][j] = __builtin_amdgcn_mfma_f32_16x16x32_bf16(kf, aq[i][kc], st[i][j], 0, 0, 0);
      }
    }

    if (kt0 + 63 > qw) {              // diagonal region: causal mask
#pragma unroll
      for (int i = 0; i < 2; ++i) {
        int q = qw + i * 16 + l15;
#pragma unroll
        for (int j = 0; j < 4; ++j) {
          int s = kt0 + j * 16 + quad * 4;
#pragma unroll
          for (int r = 0; r < 4; ++r)
            if (s + r > q) st[i][j][r] = -1e9f;
        }
      }
    }

    // online softmax; row stats live per-lane (q=l15), replicated across quads
    bf16x4 pf[2][4];
    float al[2];
#pragma unroll
    for (int i = 0; i < 2; ++i) {
      float m = -1e30f;
#pragma unroll
      for (int j = 0; j < 4; ++j)
#pragma unroll
        for (int r = 0; r < 4; ++r) m = fmaxf(m, st[i][j][r]);
      m = fmaxf(m, __shfl_xor(m, 16, 64));
      m = fmaxf(m, __shfl_xor(m, 32, 64));
      float mn = fmaxf(mst[i], m);
      al[i] = exp2f(mst[i] - mn);
      mst[i] = mn;
      float rs = 0.f;
#pragma unroll
      for (int j = 0; j < 4; ++j) {
        float p0 = exp2f(st[i][j][0] - mn);
        float p1 = exp2f(st[i][j][1] - mn);
        float p2 = exp2f(st[i][j][2] - mn);
        float p3 = exp2f(st[i][j][3] - mn);
        rs += (p0 + p1) + (p2 + p3);
        // pack 4 fp32 -> 4 bf16 via v_perm (half-up rounding)
        union { unsigned u[2]; bf16x4 v; } pk;
        pk.u[0] = __builtin_amdgcn_perm(__float_as_uint(p1) + 0x8000u,
                                        __float_as_uint(p0) + 0x8000u, 0x07060302u);
        pk.u[1] = __builtin_amdgcn_perm(__float_as_uint(p3) + 0x8000u,
                                        __float_as_uint(p2) + 0x8000u, 0x07060302u);
        pf[i][j] = pk.v;
      }
      rs += __shfl_xor(rs, 16, 64);
      rs += __shfl_xor(rs, 32, 64);
      lst[i] = lst[i] * al[i] + rs;
      // rescale O: rows of oacc are q=quad*4+r, fetch al for that row
#pragma unroll
      for (int r = 0; r < 4; ++r) {
        float a = __shfl(al[i], quad * 4 + r, 16);
#pragma unroll
        for (int n = 0; n < 8; ++n) oacc[i][n][r] *= a;
      }
    }

    // O += P*V via K=16 MFMA; P is already in A-layout in registers
#pragma unroll
    for (int j = 0; j < 4; ++j) {
#pragma unroll
      for (int n = 0; n < 8; ++n) {
        bf16x4 vf = *(const bf16x4*)&sV[(n * 16 + l15) * 72 + j * 16 + quad * 4];
#pragma unroll
        for (int i = 0; i < 2; ++i)
          oacc[i][n] = MFMA_PV(pf[i][j], vf, oacc[i][n]);
      }
    }
  }

  if (finalw) {
    // normalize + write [b, s, h, d] bf16 for the O-projection
#pragma unroll
    for (int i = 0; i < 2; ++i)
#pragma unroll
      for (int r = 0; r < 4; ++r) {
        float inv = 1.0f / __shfl(lst[i], quad * 4 + r, 16);
        int row = qw + i * 16 + quad * 4 + r;
        u16* op = attn + ((size_t)b * S_LEN + row) * HDIM + h * HEAD_D;
#pragma unroll
        for (int n = 0; n < 8; ++n)
          op[n * 16 + l15] = f2bf(oacc[i][n][r] * inv);
      }
  } else {
    // unnormalized partial O (bf16) + per-row m,l
    u16* po = pO + (size_t)slot * 16384;
#pragma unroll
    for (int i = 0; i < 2; ++i)
#pragma unroll
      for (int r = 0; r < 4; ++r) {
        int row = wave * 32 + i * 16 + quad * 4 + r;
#pragma unroll
        for (int n = 0; n < 8; ++n)
          po[row * 128 + n * 16 + l15] = f2bf(oacc[i][n][r]);
      }
    if (quad == 0) {
      float* ml = pML + slot * 256;
#pragma unroll
      for (int i = 0; i < 2; ++i) {
        int row = wave * 32 + i * 16 + l15;
        ml[row] = mst[i];
        ml[128 + row] = lst[i];
      }
    }
  }
}

// ---------------- combine the two partials of each heavy q-tile ----------------
__global__ __launch_bounds__(256) void k_attn_combine(
    const u16* __restrict__ pO, const float* __restrict__ pML,
    u16* __restrict__ attn) {
  const int bh = blockIdx.x;          // b*16 + h
  const int qt = 8 + blockIdx.y;
  const int b = bh >> 4;
  const int h = bh & 15;
  const int s0 = ((bh << 3) + blockIdx.y) << 1;   // slot pair base
  const int row = threadIdx.x >> 1;               // 0..127
  const int half = threadIdx.x & 1;               // 0..1 (64 cols each)

  const float* ml0 = pML + s0 * 256;
  const float* ml1 = pML + (s0 + 1) * 256;
  float m0 = ml0[row], l0 = ml0[128 + row];
  float m1 = ml1[row], l1 = ml1[128 + row];
  float m = fmaxf(m0, m1);
  float w0 = exp2f(m0 - m), w1 = exp2f(m1 - m);
  float inv = 1.0f / (l0 * w0 + l1 * w1);
  w0 *= inv; w1 *= inv;

  const u16* o0 = pO + (size_t)s0 * 16384 + row * 128 + half * 64;
  const u16* o1 = o0 + 16384;
  u16* op = attn + ((size_t)(b * S_LEN + (qt << 7) + row)) * HDIM + h * HEAD_D + half * 64;
#pragma unroll
  for (int k = 0; k < 8; ++k) {
    ushort4 a0 = ((const ushort4*)o0)[k * 2];
    ushort4 b0 = ((const ushort4*)o0)[k * 2 + 1];
    ushort4 a1 = ((const ushort4*)o1)[k * 2];
    ushort4 b1 = ((const ushort4*)o1)[k * 2 + 1];
    ushort4 ra, rb;
    ra.x = f2bf(bf2f(a0.x) * w0 + bf2f(a1.x) * w1);
    ra.y = f2bf(bf2f(a0.y) * w0 + bf2f(a1.y) * w1);
    ra.z = f2bf(bf2f(a0.z) * w0 + bf2f(a1.z) * w1);
    ra.w = f2bf(bf2f(a0.w) * w0 + bf2f(a1.w) * w1);
    rb.x = f2bf(bf2f(b0.x) * w0 + bf2f(b1.x) * w1);
    rb.y = f2bf(bf2f(b0.y) * w0 + bf2f(b1.y) * w1);
    rb.z = f2bf(bf2f(b0.z) * w0 + bf2f(b1.z) * w1);
    rb.w = f2bf(bf2f(b0.w) * w0 + bf2f(b1.w) * w1);
    ((ushort4*)op)[k * 2] = ra;
    ((ushort4*)op)[k * 2 + 1] = rb;
  }
}

// ---------------- launch ----------------
extern "C" void kernel_launch(void* const* d_in, const int* in_sizes, int n_in,
                              void* d_out, int out_size, void* d_ws, size_t ws_size,
                              hipStream_t stream) {
  (void)in_sizes; (void)n_in; (void)out_size; (void)ws_size;
  const float* hs = (const float*)d_in[0];
  // d_in[1] = mask (causality is computed analytically)
  const float* Wq = (const float*)d_in[2];
  const float* bq = (const float*)d_in[3];
  const float* Wk = (const float*)d_in[4];
  const float* bk = (const float*)d_in[5];
  const float* Wv = (const float*)d_in[6];
  const float* bv = (const float*)d_in[7];
  const float* Wo = (const float*)d_in[8];
  const float* bo = (const float*)d_in[9];
  float* out = (float*)d_out;

  char* ws = (char*)d_ws;
  u16* Xbf   = (u16*)(ws + 0);          // 16.8 MB
  u16* Wqt   = (u16*)(ws + 16777216);   // 8.4 MB (pi-permuted rows)
  u16* Wkt   = (u16*)(ws + 25165824);   // 2.1 MB (pi-permuted rows)
  u16* Wvt   = (u16*)(ws + 27262976);   // 2.1 MB
  u16* Wot   = (u16*)(ws + 29360128);   // 8.4 MB
  u16* Qbf   = (u16*)(ws + 88080384);   // 16.8 MB
  u16* Kbf   = (u16*)(ws + 104857600);  // 4.2 MB
  u16* Vtb   = (u16*)(ws + 109051904);  // 4.2 MB (+16B pad slack follows)
  u16* attnb = (u16*)(ws + 37748736);   // free region until k_attn
  float* pML = (float*)(ws + 54525952); // 512 slots x 256 f32 (0.5 MB)
  float2* trg = (float2*)(ws + 56623104); // 1 MB trig table
  u16* pO    = (u16*)(ws + 71303168);   // 512 x 32KB (written in k_attn)

  k_prep<<<11264, 256, 0, stream>>>(hs, Xbf, Wq, Wqt, Wk, Wkt, Wv, Wvt, Wo, Wot, trg);
  k_gemm_qkv_fused<<<dim3(32, 24), 256, 0, stream>>>(
      Xbf, Wqt, Wkt, Wvt, bq, bk, bv, Qbf, Kbf, out + 8388608,
      Vtb, out + 10485760, trg);
  k_attn<<<dim3(32, 24), 256, 0, stream>>>(Qbf, Kbf, Vtb, attnb, pO, pML);
  k_attn_combine<<<dim3(32, 8), 256, 0, stream>>>(pO, pML, attnb);
  k_gemm_o<<<dim3(32, 16), 256, 0, stream>>>(attnb, Wot, bo, out);
}

// Round 9
// 344.529 us; speedup vs baseline: 1.1611x; 1.0607x over previous
//
#include <hip/hip_runtime.h>
#include <stdint.h>

#define S_LEN 2048
#define HDIM  2048
#define N_HEADS 16
#define HEAD_D 128
#define N_KV 4

typedef unsigned short u16;
typedef __attribute__((ext_vector_type(8))) short bf16x8;
typedef __attribute__((ext_vector_type(4))) short bf16x4;
typedef __attribute__((ext_vector_type(4))) float f32x4;

// K=16 bf16 MFMA (v_mfma_f32_16x16x16_bf16, 2 A-regs = bf16x4 operands).
#define MFMA_PV(a, b, c) __builtin_amdgcn_mfma_f32_16x16x16bf16_1k(a, b, c, 0, 0, 0)

__device__ __forceinline__ u16 f2bf(float f) {
  unsigned u = __float_as_uint(f);
  u += 0x7FFFu + ((u >> 16) & 1u);
  return (u16)(u >> 16);
}

__device__ __forceinline__ float bf2f(u16 v) {
  return __uint_as_float(((unsigned)v) << 16);
}

__device__ __forceinline__ void gll16(void* lds, const void* gp) {
  __builtin_amdgcn_global_load_lds(
      (const __attribute__((address_space(1))) void*)gp,
      (__attribute__((address_space(3))) void*)lds, 16, 0, 0);
}

// ---------------- fused prep: convert + 4x weight transpose + trig table ----------------
// Block ranges: [0,8192) convert; [8192,9216) Wq; [9216,9472) Wk;
// [9472,9728) Wv; [9728,10752) Wo; [10752,11264) trig.
// perm!=0 on Wq/Wk: remap output row within each 128-col head block by
// pi(d) = (d&15) | ((d&48)<<1) | ((d&64)>>2) so rope partners (d, d+64)
// land in adjacent acc fragments of the fused GEMM epilogue.
__device__ __forceinline__ void wtrans_body(
    const float* __restrict__ W, u16* __restrict__ Wt, int K, int N,
    int perm, int flat, float (*tile)[65]) {
  int k0 = (flat & 31) * 64, n0 = (flat >> 5) * 64;
  int tr = threadIdx.x >> 6, tc = threadIdx.x & 63;
#pragma unroll
  for (int i = 0; i < 16; ++i) {
    int r = tr + i * 4;
    tile[r][tc] = W[(size_t)(k0 + r) * N + n0 + tc];
  }
  __syncthreads();
#pragma unroll
  for (int i = 0; i < 16; ++i) {
    int r = tr + i * 4;  // n offset
    int nn = n0 + r;
    if (perm)
      nn = (nn & ~127) | ((nn & 15) | ((nn & 48) << 1) | ((nn & 64) >> 2));
    Wt[(size_t)nn * K + k0 + tc] = f2bf(tile[tc][r]);
  }
}

__global__ __launch_bounds__(256) void k_prep(
    const float* __restrict__ hs, u16* __restrict__ Xbf,
    const float* __restrict__ Wq, u16* __restrict__ Wqt,
    const float* __restrict__ Wk, u16* __restrict__ Wkt,
    const float* __restrict__ Wv, u16* __restrict__ Wvt,
    const float* __restrict__ Wo, u16* __restrict__ Wot,
    float2* __restrict__ trig) {
  __shared__ float tile[64][65];
  const int bid = blockIdx.x;
  if (bid < 8192) {
    int i = bid * 256 + threadIdx.x;
    float4 v = ((const float4*)hs)[i];
    ushort4 o;
    o.x = f2bf(v.x); o.y = f2bf(v.y); o.z = f2bf(v.z); o.w = f2bf(v.w);
    ((ushort4*)Xbf)[i] = o;
  } else if (bid < 9216) {
    wtrans_body(Wq, Wqt, 2048, 2048, 1, bid - 8192, tile);
  } else if (bid < 9472) {
    wtrans_body(Wk, Wkt, 2048, 512, 1, bid - 9216, tile);
  } else if (bid < 9728) {
    wtrans_body(Wv, Wvt, 2048, 512, 0, bid - 9472, tile);
  } else if (bid < 10752) {
    wtrans_body(Wo, Wot, 2048, 2048, 0, bid - 9728, tile);
  } else {
    // RoPE trig table: full-occupancy sincosf (r5 lesson: in-epilogue
    // sincosf = OCML large-arg slow path with no TLP, +70 us).
    const float c1 = -13.287712379549449f / 64.f; // -log2(10000)/64
    int idx = (bid - 10752) * 256 + threadIdx.x;  // [0, 131072)
    int s = idx >> 6, d1 = idx & 63;
    float fr = exp2f((float)d1 * c1);
    float sn, cs;
    sincosf((float)s * fr, &sn, &cs);
    trig[idx] = make_float2(cs, sn);
  }
}

// ---------------- 128x128 bf16 MFMA GEMM mainloop (used by k_gemm_o) ----------------
__device__ __forceinline__ void gemm_main_128(
    const u16* __restrict__ A, const u16* __restrict__ Bt,
    int m0, int n0, int K, f32x4 (&acc)[4][4]) {
  __shared__ __align__(16) u16 sA[128 * 32];
  __shared__ __align__(16) u16 sB[128 * 32];
  const int tid = threadIdx.x;
  const int lane = tid & 63;
  const int wave = tid >> 6;
  const int quad = lane >> 4;
  const int l15 = lane & 15;
  const int wm = (wave >> 1) << 6;
  const int wn = (wave & 1) << 6;

#pragma unroll
  for (int i = 0; i < 4; ++i)
#pragma unroll
    for (int j = 0; j < 4; ++j)
      acc[i][j] = (f32x4){0.f, 0.f, 0.f, 0.f};

  for (int kk = 0; kk < K; kk += 32) {
    __syncthreads();
#pragma unroll
    for (int it = 0; it < 2; ++it) {
      int c = tid + (it << 8);
      int row = c >> 2;
      int ko = (c & 3) << 3;
      gll16((char*)sA + c * 16, A + (size_t)(m0 + row) * K + kk + ko);
      gll16((char*)sB + c * 16, Bt + (size_t)(n0 + row) * K + kk + ko);
    }
    __syncthreads();
    bf16x8 af[4], bfr[4];
#pragma unroll
    for (int i = 0; i < 4; ++i)
      af[i] = *(const bf16x8*)&sA[(wm + (i << 4) + l15) * 32 + quad * 8];
#pragma unroll
    for (int j = 0; j < 4; ++j)
      bfr[j] = *(const bf16x8*)&sB[(wn + (j << 4) + l15) * 32 + quad * 8];
#pragma unroll
    for (int i = 0; i < 4; ++i)
#pragma unroll
      for (int j = 0; j < 4; ++j)
        acc[i][j] = __builtin_amdgcn_mfma_f32_16x16x32_bf16(af[i], bfr[j], acc[i][j], 0, 0, 0);
  }
}

__device__ __forceinline__ void gemm_tile_128(
    const u16* __restrict__ A, const u16* __restrict__ Bt,
    const float* __restrict__ bias, float* __restrict__ C,
    int m0, int n0, int K, int ldc) {
  const int tid = threadIdx.x;
  const int lane = tid & 63;
  const int wave = tid >> 6;
  const int quad = lane >> 4;
  const int l15 = lane & 15;
  const int wm = (wave >> 1) << 6;
  const int wn = (wave & 1) << 6;

  f32x4 acc[4][4];
  gemm_main_128(A, Bt, m0, n0, K, acc);

#pragma unroll
  for (int i = 0; i < 4; ++i) {
    int row = m0 + wm + (i << 4) + quad * 4;
#pragma unroll
    for (int j = 0; j < 4; ++j) {
      int col = n0 + wn + (j << 4) + l15;
      float bv = bias[col];
      float* cp = C + (size_t)row * ldc + col;
#pragma unroll
      for (int r = 0; r < 4; ++r)
        cp[(size_t)r * ldc] = acc[i][j][r] + bv;
    }
  }
}

__global__ __launch_bounds__(256) void k_gemm_o(
    const u16* __restrict__ A, const u16* __restrict__ Wot,
    const float* __restrict__ bo, float* __restrict__ C) {
  gemm_tile_128(A, Wot, bo, C, blockIdx.x << 7, blockIdx.y << 7, 2048, 2048);
}

// ---------------- QKV GEMM: 256x256 tile, 8-wave, 8-phase counted-vmcnt ----------------
// r9: same as the r8 design with the resource-bound bug fixed.
// LAUNCH-BOUNDS LAW (empirical, this kernel family): VGPR cap ~= 512/(2*arg2)
//   (256,2)->128/120 [r0/r3], (256,3)->84 [r1]. r8's (512,2) capped VGPRs at
//   128 == sizeof(acc) alone -> full accumulator spill inside a 248-phase
//   loop -> watchdog -> container death. (512,1) -> cap 256; kernel ~200.
//  - BM=BN=256, BK=32, 512 threads (8 waves: 2M x 4N, each wave owns 128x64).
//  - LDS 64 KB static: 2 bufs x (A 16KB + B 16KB); buf = tile&1; 1 block/CU.
//  - Swizzle: phys k = k ^ ((row>>3 & 1)<<4). gll16 keeps LINEAR dest,
//    global SOURCE inverse-permuted per-lane (rule 21); ds_read same XOR.
//  - 8 phases / 2 K-tiles: {ds_read | stage -> s_barrier -> lgkmcnt(0) ->
//    setprio(1) -> 8 MFMA -> setprio(0) -> s_barrier}. Builtin barriers.
//  - counted vmcnt(2) ONLY at P4/P8 (FIFO: each retires exactly one full
//    tile); vmcnt(0) only in the peeled last iteration.
//  - Accumulation order (K ascending, 32-wide) identical to r7 => Q/K/V
//    bit-identical.
__global__ __launch_bounds__(512, 1) void k_gemm_qkv_fused(
    const u16* __restrict__ X, const u16* __restrict__ Wqt,
    const u16* __restrict__ Wkt, const u16* __restrict__ Wvt,
    const float* __restrict__ bq, const float* __restrict__ bk,
    const float* __restrict__ bv, u16* __restrict__ Qbf,
    u16* __restrict__ Kbf, float* __restrict__ outK,
    u16* __restrict__ Vt, float* __restrict__ outV,
    const float2* __restrict__ trig) {
  __shared__ __align__(16) u16 smem[32768];   // 64 KB
  const int tid = threadIdx.x;
  const int lane = tid & 63;
  const int wave = tid >> 6;
  const int quad = lane >> 4;
  const int l15 = lane & 15;
  const int wmi = wave >> 2;        // 0..1 : M-half (128 rows)
  const int wn = wave & 3;          // 0..3 : N-quarter (64 cols)
  const int m0 = blockIdx.x << 8;   // 256-row tile
  const int by = blockIdx.y;        // 0..11
  (void)lane;

  const u16* Btp; int n0l;
  if (by < 8)       { Btp = Wqt; n0l = by << 8; }
  else if (by < 10) { Btp = Wkt; n0l = (by - 8) << 8; }
  else              { Btp = Wvt; n0l = (by - 10) << 8; }
  const u16* Xp = X;

  f32x4 acc[8][4];
#pragma unroll
  for (int i = 0; i < 8; ++i)
#pragma unroll
    for (int j = 0; j < 4; ++j) acc[i][j] = (f32x4){0.f, 0.f, 0.f, 0.f};
  bf16x8 aR[4], bR[4];

  // swizzled ds_read (elements; buf stride 16384, B at +8192, row stride 32)
#define LDA_(b, row, k)                                                      \
  (*(const bf16x8*)&smem[(b) * 16384 + (row) * 32 + ((k) ^ ((((row) >> 3) & 1) << 4))])
#define LDB_(b, row, k)                                                      \
  (*(const bf16x8*)&smem[(b) * 16384 + 8192 + (row) * 32 + ((k) ^ ((((row) >> 3) & 1) << 4))])

  // stage one half-tile (8 KB = 512 x 16B, 1 load/thread), linear LDS dest,
  // inverse-swizzled global source: cl = c ^ ((c>>5 & 1)<<1) (16B chunks).
#define STGA(t, h)                                                           \
  {                                                                          \
    int c_ = tid, cl_ = c_ ^ (((c_ >> 5) & 1) << 1);                         \
    gll16((char*)smem + ((t) & 1) * 32768 + (h) * 8192 + c_ * 16,            \
          Xp + (size_t)(m0 + (h) * 128 + (cl_ >> 2)) * 2048 + (t) * 32 + (cl_ & 3) * 8); \
  }
#define STGB(t, h)                                                           \
  {                                                                          \
    int c_ = tid, cl_ = c_ ^ (((c_ >> 5) & 1) << 1);                         \
    gll16((char*)smem + ((t) & 1) * 32768 + 16384 + (h) * 8192 + c_ * 16,    \
          Btp + (size_t)(n0l + (h) * 128 + (cl_ >> 2)) * 2048 + (t) * 32 + (cl_ & 3) * 8); \
  }

#define RDA(b, ih)                                                           \
  _Pragma("unroll") for (int i_ = 0; i_ < 4; ++i_)                           \
      aR[i_] = LDA_(b, wmi * 128 + (ih) * 64 + i_ * 16 + l15, quad * 8);
#define RDB(b, jh)                                                           \
  _Pragma("unroll") for (int j_ = 0; j_ < 2; ++j_)                           \
      bR[(jh) * 2 + j_] = LDB_(b, wn * 64 + ((jh) * 2 + j_) * 16 + l15, quad * 8);
#define MM(ih, jh)                                                           \
  _Pragma("unroll") for (int i_ = 0; i_ < 4; ++i_)                           \
  _Pragma("unroll") for (int j_ = 0; j_ < 2; ++j_)                           \
      acc[(ih) * 4 + i_][(jh) * 2 + j_] = __builtin_amdgcn_mfma_f32_16x16x32_bf16( \
          aR[i_], bR[(jh) * 2 + j_], acc[(ih) * 4 + i_][(jh) * 2 + j_], 0, 0, 0);

#define PH_MID                                                               \
  __builtin_amdgcn_s_barrier();                                              \
  asm volatile("s_waitcnt lgkmcnt(0)" ::: "memory");                         \
  __builtin_amdgcn_sched_barrier(0);                                         \
  __builtin_amdgcn_s_setprio(1)
#define PH_END                                                               \
  __builtin_amdgcn_s_setprio(0);                                             \
  __builtin_amdgcn_s_barrier()

  // prologue: tile0 fully + tile1 B-halves; vmcnt(2) -> tile0 landed
  STGA(0, 0); STGA(0, 1); STGB(0, 0); STGB(0, 1);
  STGB(1, 0); STGB(1, 1);
  asm volatile("s_waitcnt vmcnt(2)" ::: "memory");
  __builtin_amdgcn_s_barrier();

  for (int it = 0; it < 31; ++it) {   // uniform iters: tiles 2it, 2it+1
    const int t1 = 2 * it + 1, tn0 = 2 * it + 2, tn1 = 2 * it + 3;
    // P1
    RDA(0, 0); RDB(0, 0); STGA(t1, 0); STGA(t1, 1);
    PH_MID; MM(0, 0); PH_END;
    // P2
    RDB(0, 1);
    PH_MID; MM(0, 1); PH_END;
    // P3
    RDA(0, 1); STGB(tn0, 0);
    PH_MID; MM(1, 1); PH_END;
    // P4
    STGB(tn0, 1);
    asm volatile("s_waitcnt vmcnt(2)" ::: "memory");
    PH_MID; MM(1, 0); PH_END;
    // P5
    RDA(1, 0); RDB(1, 0); STGA(tn0, 0); STGA(tn0, 1);
    PH_MID; MM(0, 0); PH_END;
    // P6
    RDB(1, 1);
    PH_MID; MM(0, 1); PH_END;
    // P7
    RDA(1, 1); STGB(tn1, 0);
    PH_MID; MM(1, 1); PH_END;
    // P8
    STGB(tn1, 1);
    asm volatile("s_waitcnt vmcnt(2)" ::: "memory");
    PH_MID; MM(1, 0); PH_END;
  }
  {  // peeled last iter: tiles 62, 63; no next-tile stages; drain at P4
    RDA(0, 0); RDB(0, 0); STGA(63, 0); STGA(63, 1);
    PH_MID; MM(0, 0); PH_END;
    RDB(0, 1);
    PH_MID; MM(0, 1); PH_END;
    RDA(0, 1);
    PH_MID; MM(1, 1); PH_END;
    asm volatile("s_waitcnt vmcnt(0)" ::: "memory");
    PH_MID; MM(1, 0); PH_END;
    RDA(1, 0); RDB(1, 0);
    PH_MID; MM(0, 0); PH_END;
    RDB(1, 1);
    PH_MID; MM(0, 1); PH_END;
    RDA(1, 1);
    PH_MID; MM(1, 1); PH_END;
    PH_MID; MM(1, 0); PH_END;
  }
#undef LDA_
#undef LDB_
#undef STGA
#undef STGB
#undef RDA
#undef RDB
#undef MM
#undef PH_MID
#undef PH_END

  // ---- epilogues: C rows = m0 + wmi*128 + i*16 + quad*4 + r,
  //                 C cols = n0l + wn*64 + J*16 + l15  (J = 0..3)
  if (by < 8) {
    // Q: tile covers heads 2by, 2by+1; rope pair in fragments (2jp, 2jp+1)
    const float qscale = 0.08838834764831845f * 1.4426950408889634f;
    const int h = 2 * by + (wn >> 1);
#pragma unroll
    for (int jp = 0; jp < 2; ++jp) {
      const int d1 = l15 + (((wn & 1) * 2 + jp) << 4);   // 0..63
      const float b1 = bq[h * 128 + d1];
      const float b2 = bq[h * 128 + d1 + 64];
#pragma unroll
      for (int i = 0; i < 8; ++i) {
        const int rowb = m0 + wmi * 128 + i * 16 + quad * 4;
#pragma unroll
        for (int r = 0; r < 4; ++r) {
          const int tok = rowb + r;
          const int b = tok >> 11, s = tok & 2047;
          const float2 t = trig[(s << 6) + d1];
          float x1 = acc[i][2 * jp][r] + b1;
          float x2 = acc[i][2 * jp + 1][r] + b2;
          u16* dst = Qbf + ((size_t)(b * N_HEADS + h) * S_LEN + s) * HEAD_D + d1;
          dst[0]  = f2bf((x1 * t.x - x2 * t.y) * qscale);
          dst[64] = f2bf((x1 * t.y + x2 * t.x) * qscale);
        }
      }
    }
  } else if (by < 10) {
    // K: rope + past_key fp32
    const int kvh = 2 * (by - 8) + (wn >> 1);
#pragma unroll
    for (int jp = 0; jp < 2; ++jp) {
      const int d1 = l15 + (((wn & 1) * 2 + jp) << 4);
      const float b1 = bk[kvh * 128 + d1];
      const float b2 = bk[kvh * 128 + d1 + 64];
#pragma unroll
      for (int i = 0; i < 8; ++i) {
        const int rowb = m0 + wmi * 128 + i * 16 + quad * 4;
#pragma unroll
        for (int r = 0; r < 4; ++r) {
          const int tok = rowb + r;
          const int b = tok >> 11, s = tok & 2047;
          const float2 t = trig[(s << 6) + d1];
          float x1 = acc[i][2 * jp][r] + b1;
          float x2 = acc[i][2 * jp + 1][r] + b2;
          float o1 = x1 * t.x - x2 * t.y;
          float o2 = x1 * t.y + x2 * t.x;
          size_t idx = ((size_t)(b * N_KV + kvh) * S_LEN + s) * HEAD_D + d1;
          Kbf[idx]      = f2bf(o1);
          Kbf[idx + 64] = f2bf(o2);
          outK[idx]      = o1;
          outK[idx + 64] = o2;
        }
      }
    }
  } else {
    // V: Vt bf16 [b,kvh,d,s] (ushort4 over 4 consecutive toks) + past_value
    const int kvh = 2 * (by - 10) + (wn >> 1);
#pragma unroll
    for (int i = 0; i < 8; ++i) {
      const int rowb = m0 + wmi * 128 + i * 16 + quad * 4;
      const int b = rowb >> 11, s = rowb & 2047;
      const int z = b * N_KV + kvh;
#pragma unroll
      for (int j = 0; j < 4; ++j) {
        const int d = (wn & 1) * 64 + j * 16 + l15;      // 0..127 within head
        const float bvv = bv[kvh * 128 + d];
        float v0 = acc[i][j][0] + bvv;
        float v1 = acc[i][j][1] + bvv;
        float v2 = acc[i][j][2] + bvv;
        float v3 = acc[i][j][3] + bvv;
        float* ov = outV + ((size_t)z * S_LEN + s) * HEAD_D + d;
        ov[0]   = v0;
        ov[128] = v1;
        ov[256] = v2;
        ov[384] = v3;
        ushort4 pk;
        pk.x = f2bf(v0); pk.y = f2bf(v1); pk.z = f2bf(v2); pk.w = f2bf(v3);
        *(ushort4*)(Vt + ((size_t)z * HEAD_D + d) * S_LEN + s) = pk;
      }
    }
  }
}

// ---------------- flash attention, S^T formulation, split-KV ----------------
// Round-0 form verbatim (84.5 us measured). r1-r4: (256,3) spills 211 MB
// (175 us); plain (256) floats to 172 VGPR (123 us); constant-sum decode -4%;
// dbuf+counted vmcnt -7% (2 blocks/CU already hides staging). Do not touch.
__global__ __launch_bounds__(256, 2) void k_attn(
    const u16* __restrict__ Qbf, const u16* __restrict__ Kbf,
    const u16* __restrict__ Vt, u16* __restrict__ attn,
    u16* __restrict__ pO, float* __restrict__ pML) {
  __shared__ __align__(16) u16 smem[17920];   // 35840 B
  u16* sK = smem;            // 64 x 136  (8704)
  u16* sV = smem + 8704;     // 128 x 72  (9216)

  const int tid = threadIdx.x;
  const int lane = tid & 63;
  const int wave = tid >> 6;
  const int quad = lane >> 4;
  const int l15 = lane & 15;

  const int by = blockIdx.y;
  int qt, t0, t1, slot;
  bool finalw;
  if (by < 8) {               // heavy chunk0: 16 tiles, below-diagonal only
    qt = 8 + by; t0 = 0; t1 = 16; finalw = false;
    slot = ((blockIdx.x << 3) + (qt - 8)) << 1;
  } else {
    qt = 23 - by;
    if (qt >= 8) {            // heavy chunk1: diagonal part
      t0 = 16; t1 = 2 * qt + 2; finalw = false;
      slot = (((blockIdx.x << 3) + (qt - 8)) << 1) + 1;
    } else {                  // light q-tile: whole row, direct final write
      t0 = 0; t1 = 2 * qt + 2; finalw = true; slot = 0;
    }
  }

  const int bh = blockIdx.x;
  const int b = bh >> 4;
  const int h = bh & 15;
  const int kvh = h >> 2;
  const int q0 = qt << 7;
  const int qw = q0 + wave * 32;      // this wave's first q row

  const u16* Qb = Qbf + ((size_t)(b * N_HEADS + h) * S_LEN + qw) * HEAD_D;
  const u16* Kb = Kbf + (size_t)(b * N_KV + kvh) * S_LEN * HEAD_D;
  const u16* Vb = Vt + (size_t)(b * N_KV + kvh) * HEAD_D * S_LEN;

  bf16x8 aq[2][4];
#pragma unroll
  for (int i = 0; i < 2; ++i)
#pragma unroll
    for (int kc = 0; kc < 4; ++kc)
      aq[i][kc] = *(const bf16x8*)(Qb + (size_t)(i * 16 + l15) * HEAD_D + kc * 32 + quad * 8);

  float mst[2] = {-1e30f, -1e30f}, lst[2] = {0.f, 0.f};
  f32x4 oacc[2][8];
#pragma unroll
  for (int i = 0; i < 2; ++i)
#pragma unroll
    for (int n = 0; n < 8; ++n) oacc[i][n] = (f32x4){0.f, 0.f, 0.f, 0.f};

  for (int t = t0; t < t1; ++t) {
    const int kt0 = t << 6;
    __syncthreads();
#pragma unroll
    for (int it = 0; it < 9; ++it) {
      int c = tid + (it << 8);
      if (c < 1088) {
        int row = c / 17;
        int k16 = c - row * 17;
        gll16((char*)sK + c * 16, Kb + (size_t)(kt0 + row) * HEAD_D + k16 * 8);
      } else if (c < 2240) {
        int vv = c - 1088;
        int d = vv / 9;
        int s16 = vv - d * 9;
        gll16((char*)sV + vv * 16, Vb + (size_t)d * S_LEN + kt0 + s16 * 8);
      }
    }
    __syncthreads();

    if (kt0 > qw + 31) continue;

    f32x4 st[2][4];
#pragma unroll
    for (int i = 0; i < 2; ++i)
#pragma unroll
      for (int j = 0; j < 4; ++j) st[i][j] = (f32x4){0.f, 0.f, 0.f, 0.f};
#pragma unroll
    for (int kc = 0; kc < 4; ++kc) {
#pragma unroll
      for (int j = 0; j < 4; ++j) {
        bf16x8 kf = *(const bf16x8*)&sK[(j * 16 + l15) * 136 + kc * 32 + quad * 8];
#pragma unroll
        for (int i = 0; i < 2; ++i)
          st[i][j] = __builtin_amdgcn_mfma_f32_16x16x32_bf16(kf, aq[i][kc], st[i][j], 0, 0, 0);
      }
    }

    if (kt0 + 63 > qw) {
#pragma unroll
      for (int i = 0; i < 2; ++i) {
        int q = qw + i * 16 + l15;
#pragma unroll
        for (int j = 0; j < 4; ++j) {
          int s = kt0 + j * 16 + quad * 4;
#pragma unroll
          for (int r = 0; r < 4; ++r)
            if (s + r > q) st[i][j][r] = -1e9f;
        }
      }
    }

    bf16x4 pf[2][4];
    float al[2];
#pragma unroll
    for (int i = 0; i < 2; ++i) {
      float m = -1e30f;
#pragma unroll
      for (int j = 0; j < 4; ++j)
#pragma unroll
        for (int r = 0; r < 4; ++r) m = fmaxf(m, st[i][j][r]);
      m = fmaxf(m, __shfl_xor(m, 16, 64));
      m = fmaxf(m, __shfl_xor(m, 32, 64));
      float mn = fmaxf(mst[i], m);
      al[i] = exp2f(mst[i] - mn);
      mst[i] = mn;
      float rs = 0.f;
#pragma unroll
      for (int j = 0; j < 4; ++j) {
        float p0 = exp2f(st[i][j][0] - mn);
        float p1 = exp2f(st[i][j][1] - mn);
        float p2 = exp2f(st[i][j][2] - mn);
        float p3 = exp2f(st[i][j][3] - mn);
        rs += (p0 + p1) + (p2 + p3);
        union { unsigned u[2]; bf16x4 v; } pk;
        pk.u[0] = __builtin_amdgcn_perm(__float_as_uint(p1) + 0x8000u,
                                        __float_as_uint(p0) + 0x8000u, 0x07060302u);
        pk.u[1] = __builtin_amdgcn_perm(__float_as_uint(p3) + 0x8000u,
                                        __float_as_uint(p2) + 0x8000u, 0x07060302u);
        pf[i][j] = pk.v;
      }
      rs += __shfl_xor(rs, 16, 64);
      rs += __shfl_xor(rs, 32, 64);
      lst[i] = lst[i] * al[i] + rs;
#pragma unroll
      for (int r = 0; r < 4; ++r) {
        float a = __shfl(al[i], quad * 4 + r, 16);
#pragma unroll
        for (int n = 0; n < 8; ++n) oacc[i][n][r] *= a;
      }
    }

#pragma unroll
    for (int j = 0; j < 4; ++j) {
#pragma unroll
      for (int n = 0; n < 8; ++n) {
        bf16x4 vf = *(const bf16x4*)&sV[(n * 16 + l15) * 72 + j * 16 + quad * 4];
#pragma unroll
        for (int i = 0; i < 2; ++i)
          oacc[i][n] = MFMA_PV(pf[i][j], vf, oacc[i][n]);
      }
    }
  }

  if (finalw) {
#pragma unroll
    for (int i = 0; i < 2; ++i)
#pragma unroll
      for (int r = 0; r < 4; ++r) {
        float inv = 1.0f / __shfl(lst[i], quad * 4 + r, 16);
        int row = qw + i * 16 + quad * 4 + r;
        u16* op = attn + ((size_t)b * S_LEN + row) * HDIM + h * HEAD_D;
#pragma unroll
        for (int n = 0; n < 8; ++n)
          op[n * 16 + l15] = f2bf(oacc[i][n][r] * inv);
      }
  } else {
    u16* po = pO + (size_t)slot * 16384;
#pragma unroll
    for (int i = 0; i < 2; ++i)
#pragma unroll
      for (int r = 0; r < 4; ++r) {
        int row = wave * 32 + i * 16 + quad * 4 + r;
#pragma unroll
        for (int n = 0; n < 8; ++n)
          po[row * 128 + n * 16 + l15] = f2bf(oacc[i][n][r]);
      }
    if (quad == 0) {
      float* ml = pML + slot * 256;
#pragma unroll
      for (int i = 0; i < 2; ++i) {
        int row = wave * 32 + i * 16 + l15;
        ml[row] = mst[i];
        ml[128 + row] = lst[i];
      }
    }
  }
}

// ---------------- combine the two partials of each heavy q-tile ----------------
__global__ __launch_bounds__(256) void k_attn_combine(
    const u16* __restrict__ pO, const float* __restrict__ pML,
    u16* __restrict__ attn) {
  const int bh = blockIdx.x;
  const int qt = 8 + blockIdx.y;
  const int b = bh >> 4;
  const int h = bh & 15;
  const int s0 = ((bh << 3) + blockIdx.y) << 1;
  const int row = threadIdx.x >> 1;
  const int half = threadIdx.x & 1;

  const float* ml0 = pML + s0 * 256;
  const float* ml1 = pML + (s0 + 1) * 256;
  float m0 = ml0[row], l0 = ml0[128 + row];
  float m1 = ml1[row], l1 = ml1[128 + row];
  float m = fmaxf(m0, m1);
  float w0 = exp2f(m0 - m), w1 = exp2f(m1 - m);
  float inv = 1.0f / (l0 * w0 + l1 * w1);
  w0 *= inv; w1 *= inv;

  const u16* o0 = pO + (size_t)s0 * 16384 + row * 128 + half * 64;
  const u16* o1 = o0 + 16384;
  u16* op = attn + ((size_t)(b * S_LEN + (qt << 7) + row)) * HDIM + h * HEAD_D + half * 64;
#pragma unroll
  for (int k = 0; k < 8; ++k) {
    ushort4 a0 = ((const ushort4*)o0)[k * 2];
    ushort4 b0 = ((const ushort4*)o0)[k * 2 + 1];
    ushort4 a1 = ((const ushort4*)o1)[k * 2];
    ushort4 b1 = ((const ushort4*)o1)[k * 2 + 1];
    ushort4 ra, rb;
    ra.x = f2bf(bf2f(a0.x) * w0 + bf2f(a1.x) * w1);
    ra.y = f2bf(bf2f(a0.y) * w0 + bf2f(a1.y) * w1);
    ra.z = f2bf(bf2f(a0.z) * w0 + bf2f(a1.z) * w1);
    ra.w = f2bf(bf2f(a0.w) * w0 + bf2f(a1.w) * w1);
    rb.x = f2bf(bf2f(b0.x) * w0 + bf2f(b1.x) * w1);
    rb.y = f2bf(bf2f(b0.y) * w0 + bf2f(b1.y) * w1);
    rb.z = f2bf(bf2f(b0.z) * w0 + bf2f(b1.z) * w1);
    rb.w = f2bf(bf2f(b0.w) * w0 + bf2f(b1.w) * w1);
    ((ushort4*)op)[k * 2] = ra;
    ((ushort4*)op)[k * 2 + 1] = rb;
  }
}

// ---------------- launch ----------------
extern "C" void kernel_launch(void* const* d_in, const int* in_sizes, int n_in,
                              void* d_out, int out_size, void* d_ws, size_t ws_size,
                              hipStream_t stream) {
  (void)in_sizes; (void)n_in; (void)out_size; (void)ws_size;
  const float* hs = (const float*)d_in[0];
  // d_in[1] = mask (causality is computed analytically)
  const float* Wq = (const float*)d_in[2];
  const float* bq = (const float*)d_in[3];
  const float* Wk = (const float*)d_in[4];
  const float* bk = (const float*)d_in[5];
  const float* Wv = (const float*)d_in[6];
  const float* bv = (const float*)d_in[7];
  const float* Wo = (const float*)d_in[8];
  const float* bo = (const float*)d_in[9];
  float* out = (float*)d_out;

  char* ws = (char*)d_ws;
  u16* Xbf   = (u16*)(ws + 0);          // 16.8 MB
  u16* Wqt   = (u16*)(ws + 16777216);   // 8.4 MB (pi-permuted rows)
  u16* Wkt   = (u16*)(ws + 25165824);   // 2.1 MB (pi-permuted rows)
  u16* Wvt   = (u16*)(ws + 27262976);   // 2.1 MB
  u16* Wot   = (u16*)(ws + 29360128);   // 8.4 MB
  u16* Qbf   = (u16*)(ws + 88080384);   // 16.8 MB
  u16* Kbf   = (u16*)(ws + 104857600);  // 4.2 MB
  u16* Vtb   = (u16*)(ws + 109051904);  // 4.2 MB
  u16* attnb = (u16*)(ws + 37748736);   // free region until k_attn
  float* pML = (float*)(ws + 54525952); // 512 slots x 256 f32
  float2* trg = (float2*)(ws + 56623104); // 1 MB trig table
  u16* pO    = (u16*)(ws + 71303168);   // 512 x 32KB (written in k_attn)

  k_prep<<<11264, 256, 0, stream>>>(hs, Xbf, Wq, Wqt, Wk, Wkt, Wv, Wvt, Wo, Wot, trg);
  k_gemm_qkv_fused<<<dim3(16, 12), 512, 0, stream>>>(
      Xbf, Wqt, Wkt, Wvt, bq, bk, bv, Qbf, Kbf, out + 8388608,
      Vtb, out + 10485760, trg);
  k_attn<<<dim3(32, 24), 256, 0, stream>>>(Qbf, Kbf, Vtb, attnb, pO, pML);
  k_attn_combine<<<dim3(32, 8), 256, 0, stream>>>(pO, pML, attnb);
  k_gemm_o<<<dim3(32, 16), 256, 0, stream>>>(attnb, Wot, bo, out);
}